// Round 13
// baseline (684.479 us; speedup 1.0000x reference)
//
#include <hip/hip_runtime.h>
#include <hip/hip_fp16.h>
#include <hip/hip_cooperative_groups.h>

namespace cg = cooperative_groups;

#define TT 256
#define PP 88
#define CC 128
#define NN (TT * PP)          // 22528 positions
#define NPAD (NN + 32)
#define HEADS 4
#define HD 32
#define WIN 25
#define RPBW 49
#define RPBSZ (RPBW * RPBW)   // 2401
#define SCALE 0.17677669529663687f   // 1/sqrt(32)
#define LOG2E 1.4426950408889634f
#define QSC (SCALE * LOG2E)          // fold exp->exp2 into Q path

#if __has_builtin(__builtin_amdgcn_exp2f)
#define EXP2(x) __builtin_amdgcn_exp2f(x)
#else
#define EXP2(x) exp2f(x)
#endif

typedef _Float16 f16;
typedef f16 f16x8 __attribute__((ext_vector_type(8)));
typedef f16 f16x8u __attribute__((ext_vector_type(8), aligned(4)));
typedef float f32x4 __attribute__((ext_vector_type(4)));
typedef float f32x4u __attribute__((ext_vector_type(4), aligned(4)));
typedef __fp16 hf16x2 __attribute__((ext_vector_type(2)));
union PkU { hf16x2 h; unsigned u; };

#define SMEM_BYTES 29696   // max(fusion 21504, qkv 17408, attn 2*14848)

// ---------- stage: prep (virtual blocks 0..227) ----------
__device__ __forceinline__ void prep_v(int b, int tid,
    const float* qw, const float* pw, const float* qb, const float* pbias, const float* rpb,
    f16* qwh, f16* pwh, f16* w2h, float* qbs, float* b2s, float* rpbp)
{
    if (b < 192) {
        int idx = b * 256 + tid;                      // covers 49152
        if (idx < 384 * 128) {                        // qkv W, Q rows scaled by QSC
            float v = qw[idx];
            if (idx < 128 * 128) v *= QSC;
            qwh[idx] = (f16)v;
        }
        if (idx < 128 * 128) pwh[idx] = (f16)pw[idx];
        if (idx < 384) qbs[idx] = qb[idx] * (idx < 128 ? QSC : 1.f);
        if (idx < 10240) rpbp[idx] = (idx < 4 * RPBSZ) ? rpb[idx] * LOG2E : 0.f;
    } else if (b < 216) {
        // b2s[i] = (qb[i] + qw[i,:]·pb) * sc_i ; 16 lanes per output
        int t = (b - 192) * 256 + tid;                // [0, 6144)
        int i = t >> 4, l = t & 15;
        if (i < 384) {
            float s = 0.f;
            #pragma unroll
            for (int j = l * 8; j < l * 8 + 8; j++) s += qw[i * 128 + j] * pbias[j];
            s += __shfl_xor(s, 1); s += __shfl_xor(s, 2);
            s += __shfl_xor(s, 4); s += __shfl_xor(s, 8);
            if (l == 0) b2s[i] = (qb[i] + s) * (i < 128 ? QSC : 1.f);
        }
    } else {
        // w2h[i][k] = sc_i * sum_j qw[i][j] pw[j][k]
        const int bw = b - 216;                       // 0..11
        const int m0 = (bw & 1) * 64;                 // k-tile
        const int n0 = (bw >> 1) * 64;                // i-tile
        const int w = tid >> 6, lane = tid & 63, quad = lane >> 4, nn = lane & 15;
        const int krow = m0 + w * 16 + nn;
        f16x8 af[4];
        #pragma unroll
        for (int ks = 0; ks < 4; ks++) {
            union { f16 e[8]; f16x8 v; } t;
            #pragma unroll
            for (int e = 0; e < 8; e++)
                t.e[e] = (f16)pw[(ks * 32 + quad * 8 + e) * 128 + krow];
            af[ks] = t.v;
        }
        f32x4 acc[4] = {};
        #pragma unroll
        for (int nt = 0; nt < 4; nt++) {
            int irow = n0 + nt * 16 + nn;
            #pragma unroll
            for (int ks = 0; ks < 4; ks++) {
                const float* qr = &qw[(size_t)irow * 128 + ks * 32 + quad * 8];
                float4 a = *(const float4*)qr, bq = *(const float4*)(qr + 4);
                PkU u0, u1, u2, u3;
                u0.h = __builtin_amdgcn_cvt_pkrtz(a.x, a.y);
                u1.h = __builtin_amdgcn_cvt_pkrtz(a.z, a.w);
                u2.h = __builtin_amdgcn_cvt_pkrtz(bq.x, bq.y);
                u3.h = __builtin_amdgcn_cvt_pkrtz(bq.z, bq.w);
                union { unsigned u[4]; f16x8 v; } bb;
                bb.u[0] = u0.u; bb.u[1] = u1.u; bb.u[2] = u2.u; bb.u[3] = u3.u;
                acc[nt] = __builtin_amdgcn_mfma_f32_16x16x32_f16(af[ks], bb.v, acc[nt], 0, 0, 0);
            }
        }
        #pragma unroll
        for (int nt = 0; nt < 4; nt++) {
            int i = n0 + nt * 16 + nn;
            float sc = (i < 128) ? QSC : 1.f;
            PkU p0, p1;
            p0.h = __builtin_amdgcn_cvt_pkrtz(acc[nt][0] * sc, acc[nt][1] * sc);
            p1.h = __builtin_amdgcn_cvt_pkrtz(acc[nt][2] * sc, acc[nt][3] * sc);
            *(uint2*)&w2h[(size_t)i * 128 + m0 + w * 16 + quad * 4] = make_uint2(p0.u, p1.u);
        }
    }
}

// ---------- stage: fusion (virtual 0..703); weights read from fp32 lw inline ----------
__device__ __forceinline__ void fusion_v(int vb, int tid, char* smem,
    const float* x, const float* cond, const float* mask,
    const float* lw, const float* lb, f16* yh)
{
    f16* Alds = (f16*)smem;   // [64][168]
    const int m0 = (vb >> 1) * 64, n0 = (vb & 1) * 64;
    const int w = tid >> 6, lane = tid & 63, quad = lane >> 4, nn = lane & 15;

    {   // stage cat rows (f16)
        int r = tid >> 2, cpart = tid & 3;
        size_t pos = m0 + r;
        *(uint4*)&Alds[r * 168 + 128 + cpart * 8] = make_uint4(0, 0, 0, 0);
        const float* xr = x + pos * 128 + cpart * 32;
        #pragma unroll
        for (int t = 0; t < 4; t++) {
            float4 a = *(const float4*)(xr + t * 8);
            float4 b = *(const float4*)(xr + t * 8 + 4);
            PkU p0, p1, p2, p3;
            p0.h = __builtin_amdgcn_cvt_pkrtz(a.x, a.y);
            p1.h = __builtin_amdgcn_cvt_pkrtz(a.z, a.w);
            p2.h = __builtin_amdgcn_cvt_pkrtz(b.x, b.y);
            p3.h = __builtin_amdgcn_cvt_pkrtz(b.z, b.w);
            *(uint4*)&Alds[r * 168 + cpart * 32 + t * 8] = make_uint4(p0.u, p1.u, p2.u, p3.u);
        }
        if (cpart == 0) {
            Alds[r * 168 + 128] = (f16)cond[pos * 2];
            Alds[r * 168 + 129] = (f16)cond[pos * 2 + 1];
            Alds[r * 168 + 130] = (f16)mask[pos];
        }
    }
    __syncthreads();

    const int oc = n0 + w * 16 + nn;
    f16x8 af[5];
    #pragma unroll
    for (int ks = 0; ks < 5; ks++) {
        union { f16 e[8]; f16x8 v; } t;
        #pragma unroll
        for (int j = 0; j < 8; j++) {
            int k = ks * 32 + quad * 8 + j;
            t.e[j] = (k < 131) ? (f16)lw[oc * 131 + k] : (f16)0.f;
        }
        af[ks] = t.v;
    }
    f32x4 acc[4] = {};
    #pragma unroll
    for (int ks = 0; ks < 5; ks++)
        #pragma unroll
        for (int nt = 0; nt < 4; nt++) {
            f16x8 bf = *(const f16x8*)&Alds[(nt * 16 + nn) * 168 + ks * 32 + quad * 8];
            acc[nt] = __builtin_amdgcn_mfma_f32_16x16x32_f16(af[ks], bf, acc[nt], 0, 0, 0);
        }
    float bv[4];
    #pragma unroll
    for (int r = 0; r < 4; r++) bv[r] = lb[n0 + w * 16 + quad * 4 + r];
    #pragma unroll
    for (int nt = 0; nt < 4; nt++) {
        int pos = m0 + nt * 16 + nn;
        PkU p0, p1;
        p0.h = __builtin_amdgcn_cvt_pkrtz(fmaxf(acc[nt][0] + bv[0], 0.f), fmaxf(acc[nt][1] + bv[1], 0.f));
        p1.h = __builtin_amdgcn_cvt_pkrtz(fmaxf(acc[nt][2] + bv[2], 0.f), fmaxf(acc[nt][3] + bv[3], 0.f));
        *(uint2*)&yh[(size_t)pos * 128 + n0 + w * 16 + quad * 4] = make_uint2(p0.u, p1.u);
    }
    __syncthreads();   // LDS reuse safety across persistent-loop iterations
}

// ---------- stage: qkv GEMM (virtual 0..2111); Q|K rows stride 256, V transposed ----------
__device__ __forceinline__ void qkv_v(int vb, int tid, char* smem,
    const f16* A, const f16* W, const float* bias, f16* qkh, f16* vt)
{
    f16* Alds = (f16*)smem;   // [64][136]
    const int by = vb / 352, bx = vb - by * 352;
    const int m0 = bx * 64, n0 = by * 64;
    const int w = tid >> 6, lane = tid & 63, quad = lane >> 4, nn = lane & 15;

    for (int i = tid; i < 1024; i += 256) {
        int r = i >> 4, c = i & 15;
        *(uint4*)&Alds[r * 136 + c * 8] = *(const uint4*)&A[(size_t)(m0 + r) * 128 + c * 8];
    }
    __syncthreads();

    const int oc = n0 + w * 16 + nn;
    f16x8 af[4];
    #pragma unroll
    for (int ks = 0; ks < 4; ks++)
        af[ks] = *(const f16x8*)&W[(size_t)oc * 128 + ks * 32 + quad * 8];
    f32x4 acc[4] = {};
    #pragma unroll
    for (int ks = 0; ks < 4; ks++)
        #pragma unroll
        for (int nt = 0; nt < 4; nt++) {
            f16x8 bf = *(const f16x8*)&Alds[(nt * 16 + nn) * 136 + ks * 32 + quad * 8];
            acc[nt] = __builtin_amdgcn_mfma_f32_16x16x32_f16(af[ks], bf, acc[nt], 0, 0, 0);
        }
    float bv[4];
    #pragma unroll
    for (int r = 0; r < 4; r++) bv[r] = bias[n0 + w * 16 + quad * 4 + r];

    if (n0 < 256) {
        #pragma unroll
        for (int nt = 0; nt < 4; nt++) {
            int pos = m0 + nt * 16 + nn;
            PkU p0, p1;
            p0.h = __builtin_amdgcn_cvt_pkrtz(acc[nt][0] + bv[0], acc[nt][1] + bv[1]);
            p1.h = __builtin_amdgcn_cvt_pkrtz(acc[nt][2] + bv[2], acc[nt][3] + bv[3]);
            *(uint2*)&qkh[(size_t)pos * 256 + n0 + w * 16 + quad * 4] = make_uint2(p0.u, p1.u);
        }
    } else {
        #pragma unroll
        for (int nt = 0; nt < 4; nt++) {
            int pos = m0 + nt * 16 + nn;
            #pragma unroll
            for (int r = 0; r < 4; r++) {
                int chg = n0 - 256 + w * 16 + quad * 4 + r;
                vt[(size_t)chg * NPAD + pos] = (f16)(acc[nt][r] + bv[r]);
            }
        }
    }
    __syncthreads();   // LDS reuse safety
}

// ---------- stage: final projection (virtual 0..703), fp32 out ----------
__device__ __forceinline__ void out_v(int vb, int tid, char* smem,
    const f16* A, const f16* W, const float* bias, float* outp)
{
    f16* Alds = (f16*)smem;   // [64][136]
    const int m0 = (vb >> 1) * 64, n0 = (vb & 1) * 64;
    const int w = tid >> 6, lane = tid & 63, quad = lane >> 4, nn = lane & 15;

    for (int i = tid; i < 1024; i += 256) {
        int r = i >> 4, c = i & 15;
        *(uint4*)&Alds[r * 136 + c * 8] = *(const uint4*)&A[(size_t)(m0 + r) * 128 + c * 8];
    }
    __syncthreads();

    const int oc = n0 + w * 16 + nn;
    f16x8 af[4];
    #pragma unroll
    for (int ks = 0; ks < 4; ks++)
        af[ks] = *(const f16x8*)&W[(size_t)oc * 128 + ks * 32 + quad * 8];
    f32x4 acc[4] = {};
    #pragma unroll
    for (int ks = 0; ks < 4; ks++)
        #pragma unroll
        for (int nt = 0; nt < 4; nt++) {
            f16x8 bf = *(const f16x8*)&Alds[(nt * 16 + nn) * 136 + ks * 32 + quad * 8];
            acc[nt] = __builtin_amdgcn_mfma_f32_16x16x32_f16(af[ks], bf, acc[nt], 0, 0, 0);
        }
    float bv[4];
    #pragma unroll
    for (int r = 0; r < 4; r++) bv[r] = bias[n0 + w * 16 + quad * 4 + r];
    #pragma unroll
    for (int nt = 0; nt < 4; nt++) {
        int pos = m0 + nt * 16 + nn;
        f32x4 vv;
        #pragma unroll
        for (int r = 0; r < 4; r++) vv[r] = acc[nt][r] + bv[r];
        *(f32x4*)&outp[(size_t)pos * 128 + n0 + w * 16 + quad * 4] = vv;
    }
    __syncthreads();   // LDS reuse safety
}

// ---------- stage: attention (virtual 0..1407; two 128-thread tasks per block) ----------
__device__ __forceinline__ void attn_v(int va, int tid256, char* lds,
    const f16* qkh, const f16* vt, const float* rpbp, f16* ao)
{
    const int half = tid256 >> 7;
    const int tid = tid256 & 127;
    char* base = lds + half * 14848;
    f16 (*Plds)[40] = (f16 (*)[40])base;              // [2*16][40]
    float (*Olds)[48] = (float (*)[48])(base + 2560); // [64][48]

    const int hh = va / 352;
    const int rr = va - hh * 352;
    const int i0 = (rr & 31) * 8;
    const int j0 = (rr >> 5) * 8;

    const int w = tid >> 6, lane = tid & 63;
    const int quad = lane >> 4, nn = lane & 15;

    const int ri0 = min(max(i0 - 12, 0), TT - 32);
    const int rj0 = min(max(j0 - 12, 0), PP - WIN) & ~1;

    int qi_[4], si_[4], dbb_[4];
    unsigned cm_[4];
    f16x8 qf[4];
    #pragma unroll
    for (int qs = 0; qs < 4; qs++) {
        int ql = qs * 16 + nn;
        int qi = i0 + (ql >> 3), qj = j0 + (ql & 7);
        int si = min(max(qi - 12, 0), TT - WIN);
        int sj = min(max(qj - 12, 0), PP - WIN);
        qi_[qs] = qi; si_[qs] = si;
        cm_[qs] = 0x1FFFFFFu << (sj - rj0);
        dbb_[qs] = rj0 - qj + 24;
        qf[qs] = *(const f16x8*)&qkh[(size_t)(qi * PP + qj) * 256 + hh * HD + quad * 8];
    }
    const float* rp_h = rpbp + hh * RPBSZ;
    const f16* vbase = vt + (size_t)(hh * HD + nn) * NPAD;
    const f16x8 onesv = {(f16)1.f, (f16)1.f, (f16)1.f, (f16)1.f,
                         (f16)1.f, (f16)1.f, (f16)1.f, (f16)1.f};

    f32x4 O[4][2] = {};
    f32x4 lacc[4] = {};

    const int b0 = min(rj0 + nn, PP - 1);
    const int b1 = min(rj0 + 16 + nn, PP - 1);
    const size_t koff = 128 + hh * HD + quad * 8;

    int aa = ri0 + w * 16;
    const f16* rowK = qkh + (size_t)aa * PP * 256 + koff;
    f16x8 kf0 = *(const f16x8*)(rowK + (size_t)b0 * 256);
    f16x8 kf1 = *(const f16x8*)(rowK + (size_t)b1 * 256);
    const f16* vrow = vbase + aa * PP + rj0 + quad * 8;
    f16x8 vf0 = *(const f16x8u*)vrow;
    f16x8 vf1 = *(const f16x8u*)(vrow + (size_t)16 * NPAD);

    for (int c = 0; c < 16; c++) {
        // prefetch chunk aa+1 (last-iter overshoot lands in vt/ao scratch: unused)
        const f16* rowKn = qkh + (size_t)(aa + 1) * PP * 256 + koff;
        f16x8 nkf0 = *(const f16x8*)(rowKn + (size_t)b0 * 256);
        f16x8 nkf1 = *(const f16x8*)(rowKn + (size_t)b1 * 256);
        const f16* vrown = vbase + (aa + 1) * PP + rj0 + quad * 8;
        f16x8 nvf0 = *(const f16x8u*)vrown;
        f16x8 nvf1 = *(const f16x8u*)(vrown + (size_t)16 * NPAD);

        #pragma unroll
        for (int qs = 0; qs < 4; qs++) {
            unsigned vm = ((unsigned)(aa - si_[qs]) <= 24u) ? cm_[qs] : 0u;
            const float* rp = rp_h + (aa - qi_[qs] + 24) * RPBW + dbb_[qs];
            f32x4 ra = *(const f32x4u*)(rp + quad * 4);
            f32x4 rb = *(const f32x4u*)(rp + 16 + quad * 4);
            f32x4 za, zb;
            #pragma unroll
            for (int r = 0; r < 4; r++) {
                int kl0 = quad * 4 + r;
                za[r] = ((vm >> kl0) & 1u) ? ra[r] : -1e30f;
                zb[r] = ((vm >> (kl0 + 16)) & 1u) ? rb[r] : -1e30f;
            }
            f32x4 s0 = __builtin_amdgcn_mfma_f32_16x16x32_f16(kf0, qf[qs], za, 0, 0, 0);
            f32x4 s1 = __builtin_amdgcn_mfma_f32_16x16x32_f16(kf1, qf[qs], zb, 0, 0, 0);

            float p[8];
            #pragma unroll
            for (int r = 0; r < 4; r++) {
                p[r]     = EXP2(s0[r]);
                p[r + 4] = EXP2(s1[r]);
            }
            PkU a, b, cc, d;
            a.h  = __builtin_amdgcn_cvt_pkrtz(p[0], p[1]);
            b.h  = __builtin_amdgcn_cvt_pkrtz(p[2], p[3]);
            cc.h = __builtin_amdgcn_cvt_pkrtz(p[4], p[5]);
            d.h  = __builtin_amdgcn_cvt_pkrtz(p[6], p[7]);
            *(uint2*)&Plds[w * 16 + nn][quad * 4]      = make_uint2(a.u, b.u);
            *(uint2*)&Plds[w * 16 + nn][16 + quad * 4] = make_uint2(cc.u, d.u);
            f16x8 pf = *(const f16x8*)&Plds[w * 16 + nn][quad * 8];

            O[qs][0] = __builtin_amdgcn_mfma_f32_16x16x32_f16(pf, vf0, O[qs][0], 0, 0, 0);
            O[qs][1] = __builtin_amdgcn_mfma_f32_16x16x32_f16(pf, vf1, O[qs][1], 0, 0, 0);
            lacc[qs] = __builtin_amdgcn_mfma_f32_16x16x32_f16(pf, onesv, lacc[qs], 0, 0, 0);
        }
        kf0 = nkf0; kf1 = nkf1; vf0 = nvf0; vf1 = nvf1;
        aa++;
    }

    __syncthreads();   // previous-iteration Olds reads complete before new stores
    if (w == 1) {
        float* ob = Olds[lane];
        #pragma unroll
        for (int qs = 0; qs < 4; qs++) {
            *(f32x4*)&ob[qs * 12]     = O[qs][0];
            *(f32x4*)&ob[qs * 12 + 4] = O[qs][1];
            *(f32x4*)&ob[qs * 12 + 8] = lacc[qs];
        }
    }
    __syncthreads();
    if (w == 0) {
        const float* ob = Olds[lane];
        #pragma unroll
        for (int qs = 0; qs < 4; qs++) {
            O[qs][0] += *(const f32x4*)&ob[qs * 12];
            O[qs][1] += *(const f32x4*)&ob[qs * 12 + 4];
            lacc[qs] += *(const f32x4*)&ob[qs * 12 + 8];
            #pragma unroll
            for (int r = 0; r < 4; r++) {
                float li = 1.f / lacc[qs][r];
                int ql = qs * 16 + quad * 4 + r;
                int qi = i0 + (ql >> 3), qj = j0 + (ql & 7);
                size_t base2 = (size_t)(qi * PP + qj) * CC + hh * HD;
                ao[base2 + nn]      = (f16)(O[qs][0][r] * li);
                ao[base2 + 16 + nn] = (f16)(O[qs][1][r] * li);
            }
        }
    }
}

// ---------- the cooperative mega-kernel ----------
__global__ __launch_bounds__(256, 4) void mega(
    const float* __restrict__ x, const float* __restrict__ cond, const float* __restrict__ mask,
    const float* __restrict__ lw, const float* __restrict__ lb,
    const float* __restrict__ qw, const float* __restrict__ qb,
    const float* __restrict__ rpb, const float* __restrict__ pw, const float* __restrict__ pbias,
    float* __restrict__ outp,
    float* qbs, float* b2s, float* rpbp,
    f16* qwh, f16* pwh, f16* w2h, f16* yh, f16* qkh, f16* vt, f16* ao)
{
    __shared__ __align__(16) char smem[SMEM_BYTES];
    cg::grid_group grid = cg::this_grid();
    const int tid = threadIdx.x;
    const int pbk = blockIdx.x;
    const int nb = gridDim.x;

    // S1: prep (0..227) || fusion (228..931)
    for (int vb = pbk; vb < 932; vb += nb) {
        if (vb < 228) prep_v(vb, tid, qw, pw, qb, pbias, rpb, qwh, pwh, w2h, qbs, b2s, rpbp);
        else fusion_v(vb - 228, tid, smem, x, cond, mask, lw, lb, yh);
    }
    grid.sync();
    // S2: qkv layer 1
    for (int vb = pbk; vb < 2112; vb += nb) qkv_v(vb, tid, smem, yh, qwh, qbs, qkh, vt);
    grid.sync();
    // S3: attention layer 1
    for (int t = pbk; t < 704; t += nb) attn_v(t * 2 + (tid >> 7), tid, smem, qkh, vt, rpbp, ao);
    grid.sync();
    // S4: fused proj+qkv layer 2
    for (int vb = pbk; vb < 2112; vb += nb) qkv_v(vb, tid, smem, ao, w2h, b2s, qkh, vt);
    grid.sync();
    // S5: attention layer 2
    for (int t = pbk; t < 704; t += nb) attn_v(t * 2 + (tid >> 7), tid, smem, qkh, vt, rpbp, ao);
    grid.sync();
    // S6: output projection
    for (int vb = pbk; vb < 704; vb += nb) out_v(vb, tid, smem, ao, pwh, pbias, outp);
}

extern "C" void kernel_launch(void* const* d_in, const int* in_sizes, int n_in,
                              void* d_out, int out_size, void* d_ws, size_t ws_size,
                              hipStream_t stream) {
    (void)in_sizes; (void)n_in; (void)out_size; (void)ws_size;
    const float* x    = (const float*)d_in[0];
    const float* cond = (const float*)d_in[1];
    const float* mask = (const float*)d_in[2];
    const float* lw   = (const float*)d_in[3];
    const float* lb   = (const float*)d_in[4];
    const float* qw   = (const float*)d_in[5];
    const float* qb   = (const float*)d_in[6];
    const float* rpb  = (const float*)d_in[7];
    const float* pw   = (const float*)d_in[8];
    const float* pbias = (const float*)d_in[9];
    float* outp       = (float*)d_out;

    float* ws   = (float*)d_ws;
    float* qbs  = ws;                             // 384
    float* b2s  = qbs + 384;                      // 384
    float* rpbp = b2s + 384;                      // 10240 padded (stray negative-index reads hit qbs/b2s: finite, masked)
    f16* qwh  = (f16*)(rpbp + 10240);             // 384*128
    f16* pwh  = qwh + 49152;                      // 128*128
    f16* w2h  = pwh + 16384;                      // 384*128
    f16* yh   = w2h + 49152;                      // NN*128
    f16* qkh  = yh + (size_t)NN * 128;            // NN*256 (Q|K)
    f16* vt   = qkh + (size_t)NN * 256;           // 128*NPAD
    f16* ao   = vt + (size_t)128 * NPAD;          // NN*128 (prefetch overshoot lands in vt/ao)

    int bpc = 0;
    hipOccupancyMaxActiveBlocksPerMultiprocessor(&bpc, (const void*)mega, 256, 0);
    if (bpc < 1) bpc = 1;
    int nsm = 256;
    hipDeviceProp_t prop;
    int dev = 0;
    if (hipGetDevice(&dev) == hipSuccess && hipGetDeviceProperties(&prop, dev) == hipSuccess)
        nsm = prop.multiProcessorCount;
    long long nbl = (long long)bpc * nsm;
    if (nbl > 2112) nbl = 2112;
    dim3 gridDim((unsigned)nbl), blockDim(256);

    void* args[] = {
        (void*)&x, (void*)&cond, (void*)&mask, (void*)&lw, (void*)&lb,
        (void*)&qw, (void*)&qb, (void*)&rpb, (void*)&pw, (void*)&pbias,
        (void*)&outp, (void*)&qbs, (void*)&b2s, (void*)&rpbp,
        (void*)&qwh, (void*)&pwh, (void*)&w2h, (void*)&yh, (void*)&qkh,
        (void*)&vt, (void*)&ao
    };
    hipLaunchCooperativeKernel((const void*)mega, gridDim, blockDim, args, 0, stream);
}

// Round 15
// 584.504 us; speedup vs baseline: 1.1710x; 1.1710x over previous
//
#include <hip/hip_runtime.h>
#include <hip/hip_fp16.h>
#include <hip/hip_cooperative_groups.h>

namespace cg = cooperative_groups;

#define TT 256
#define PP 88
#define CC 128
#define NN (TT * PP)          // 22528 positions
#define NPAD (NN + 32)
#define HEADS 4
#define HD 32
#define WIN 25
#define RPBW 49
#define RPBSZ (RPBW * RPBW)   // 2401
#define SCALE 0.17677669529663687f   // 1/sqrt(32)
#define LOG2E 1.4426950408889634f
#define QSC (SCALE * LOG2E)          // fold exp->exp2 into Q path

#if __has_builtin(__builtin_amdgcn_exp2f)
#define EXP2(x) __builtin_amdgcn_exp2f(x)
#else
#define EXP2(x) exp2f(x)
#endif

typedef _Float16 f16;
typedef f16 f16x8 __attribute__((ext_vector_type(8)));
typedef f16 f16x8u __attribute__((ext_vector_type(8), aligned(4)));
typedef float f32x4 __attribute__((ext_vector_type(4)));
typedef float f32x4u __attribute__((ext_vector_type(4), aligned(4)));
typedef __fp16 hf16x2 __attribute__((ext_vector_type(2)));
union PkU { hf16x2 h; unsigned u; };

#define SMEM_BYTES 29696   // max(fusion 21504, qkv 17408, attn 2*14848)

// ---------- stage: prep (virtual blocks 0..227) ----------
__device__ __forceinline__ void prep_v(int b, int tid,
    const float* qw, const float* pw, const float* qb, const float* pbias, const float* rpb,
    f16* qwh, f16* pwh, f16* w2h, float* qbs, float* b2s, float* rpbp)
{
    if (b < 192) {
        int idx = b * 256 + tid;                      // covers 49152
        if (idx < 384 * 128) {                        // qkv W, Q rows scaled by QSC
            float v = qw[idx];
            if (idx < 128 * 128) v *= QSC;
            qwh[idx] = (f16)v;
        }
        if (idx < 128 * 128) pwh[idx] = (f16)pw[idx];
        if (idx < 384) qbs[idx] = qb[idx] * (idx < 128 ? QSC : 1.f);
        if (idx < 10240) rpbp[idx] = (idx < 4 * RPBSZ) ? rpb[idx] * LOG2E : 0.f;
    } else if (b < 216) {
        // b2s[i] = (qb[i] + qw[i,:]·pb) * sc_i ; 16 lanes per output
        int t = (b - 192) * 256 + tid;                // [0, 6144)
        int i = t >> 4, l = t & 15;
        if (i < 384) {
            float s = 0.f;
            #pragma unroll
            for (int j = l * 8; j < l * 8 + 8; j++) s += qw[i * 128 + j] * pbias[j];
            s += __shfl_xor(s, 1); s += __shfl_xor(s, 2);
            s += __shfl_xor(s, 4); s += __shfl_xor(s, 8);
            if (l == 0) b2s[i] = (qb[i] + s) * (i < 128 ? QSC : 1.f);
        }
    } else {
        // w2h[i][k] = sc_i * sum_j qw[i][j] pw[j][k]
        const int bw = b - 216;                       // 0..11
        const int m0 = (bw & 1) * 64;                 // k-tile
        const int n0 = (bw >> 1) * 64;                // i-tile
        const int w = tid >> 6, lane = tid & 63, quad = lane >> 4, nn = lane & 15;
        const int krow = m0 + w * 16 + nn;
        f16x8 af[4];
        #pragma unroll
        for (int ks = 0; ks < 4; ks++) {
            union { f16 e[8]; f16x8 v; } t;
            #pragma unroll
            for (int e = 0; e < 8; e++)
                t.e[e] = (f16)pw[(ks * 32 + quad * 8 + e) * 128 + krow];
            af[ks] = t.v;
        }
        f32x4 acc[4] = {};
        #pragma unroll
        for (int nt = 0; nt < 4; nt++) {
            int irow = n0 + nt * 16 + nn;
            #pragma unroll
            for (int ks = 0; ks < 4; ks++) {
                const float* qr = &qw[(size_t)irow * 128 + ks * 32 + quad * 8];
                float4 a = *(const float4*)qr, bq = *(const float4*)(qr + 4);
                PkU u0, u1, u2, u3;
                u0.h = __builtin_amdgcn_cvt_pkrtz(a.x, a.y);
                u1.h = __builtin_amdgcn_cvt_pkrtz(a.z, a.w);
                u2.h = __builtin_amdgcn_cvt_pkrtz(bq.x, bq.y);
                u3.h = __builtin_amdgcn_cvt_pkrtz(bq.z, bq.w);
                union { unsigned u[4]; f16x8 v; } bb;
                bb.u[0] = u0.u; bb.u[1] = u1.u; bb.u[2] = u2.u; bb.u[3] = u3.u;
                acc[nt] = __builtin_amdgcn_mfma_f32_16x16x32_f16(af[ks], bb.v, acc[nt], 0, 0, 0);
            }
        }
        #pragma unroll
        for (int nt = 0; nt < 4; nt++) {
            int i = n0 + nt * 16 + nn;
            float sc = (i < 128) ? QSC : 1.f;
            PkU p0, p1;
            p0.h = __builtin_amdgcn_cvt_pkrtz(acc[nt][0] * sc, acc[nt][1] * sc);
            p1.h = __builtin_amdgcn_cvt_pkrtz(acc[nt][2] * sc, acc[nt][3] * sc);
            *(uint2*)&w2h[(size_t)i * 128 + m0 + w * 16 + quad * 4] = make_uint2(p0.u, p1.u);
        }
    }
}

// ---------- stage: fusion (virtual 0..703); weights read from fp32 lw inline ----------
__device__ __forceinline__ void fusion_v(int vb, int tid, char* smem,
    const float* x, const float* cond, const float* mask,
    const float* lw, const float* lb, f16* yh)
{
    f16* Alds = (f16*)smem;   // [64][168]
    const int m0 = (vb >> 1) * 64, n0 = (vb & 1) * 64;
    const int w = tid >> 6, lane = tid & 63, quad = lane >> 4, nn = lane & 15;

    {   // stage cat rows (f16)
        int r = tid >> 2, cpart = tid & 3;
        size_t pos = m0 + r;
        *(uint4*)&Alds[r * 168 + 128 + cpart * 8] = make_uint4(0, 0, 0, 0);
        const float* xr = x + pos * 128 + cpart * 32;
        #pragma unroll
        for (int t = 0; t < 4; t++) {
            float4 a = *(const float4*)(xr + t * 8);
            float4 b = *(const float4*)(xr + t * 8 + 4);
            PkU p0, p1, p2, p3;
            p0.h = __builtin_amdgcn_cvt_pkrtz(a.x, a.y);
            p1.h = __builtin_amdgcn_cvt_pkrtz(a.z, a.w);
            p2.h = __builtin_amdgcn_cvt_pkrtz(b.x, b.y);
            p3.h = __builtin_amdgcn_cvt_pkrtz(b.z, b.w);
            *(uint4*)&Alds[r * 168 + cpart * 32 + t * 8] = make_uint4(p0.u, p1.u, p2.u, p3.u);
        }
        if (cpart == 0) {
            Alds[r * 168 + 128] = (f16)cond[pos * 2];
            Alds[r * 168 + 129] = (f16)cond[pos * 2 + 1];
            Alds[r * 168 + 130] = (f16)mask[pos];
        }
    }
    __syncthreads();

    const int oc = n0 + w * 16 + nn;
    f16x8 af[5];
    #pragma unroll
    for (int ks = 0; ks < 5; ks++) {
        union { f16 e[8]; f16x8 v; } t;
        #pragma unroll
        for (int j = 0; j < 8; j++) {
            int k = ks * 32 + quad * 8 + j;
            t.e[j] = (k < 131) ? (f16)lw[oc * 131 + k] : (f16)0.f;
        }
        af[ks] = t.v;
    }
    f32x4 acc[4] = {};
    #pragma unroll
    for (int ks = 0; ks < 5; ks++)
        #pragma unroll
        for (int nt = 0; nt < 4; nt++) {
            f16x8 bf = *(const f16x8*)&Alds[(nt * 16 + nn) * 168 + ks * 32 + quad * 8];
            acc[nt] = __builtin_amdgcn_mfma_f32_16x16x32_f16(af[ks], bf, acc[nt], 0, 0, 0);
        }
    float bv[4];
    #pragma unroll
    for (int r = 0; r < 4; r++) bv[r] = lb[n0 + w * 16 + quad * 4 + r];
    #pragma unroll
    for (int nt = 0; nt < 4; nt++) {
        int pos = m0 + nt * 16 + nn;
        PkU p0, p1;
        p0.h = __builtin_amdgcn_cvt_pkrtz(fmaxf(acc[nt][0] + bv[0], 0.f), fmaxf(acc[nt][1] + bv[1], 0.f));
        p1.h = __builtin_amdgcn_cvt_pkrtz(fmaxf(acc[nt][2] + bv[2], 0.f), fmaxf(acc[nt][3] + bv[3], 0.f));
        *(uint2*)&yh[(size_t)pos * 128 + n0 + w * 16 + quad * 4] = make_uint2(p0.u, p1.u);
    }
    __syncthreads();   // LDS reuse safety across persistent-loop iterations
}

// ---------- stage: qkv GEMM (virtual 0..2111); Q|K rows stride 256, V transposed ----------
__device__ __forceinline__ void qkv_v(int vb, int tid, char* smem,
    const f16* A, const f16* W, const float* bias, f16* qkh, f16* vt)
{
    f16* Alds = (f16*)smem;   // [64][136]
    const int by = vb / 352, bx = vb - by * 352;
    const int m0 = bx * 64, n0 = by * 64;
    const int w = tid >> 6, lane = tid & 63, quad = lane >> 4, nn = lane & 15;

    for (int i = tid; i < 1024; i += 256) {
        int r = i >> 4, c = i & 15;
        *(uint4*)&Alds[r * 136 + c * 8] = *(const uint4*)&A[(size_t)(m0 + r) * 128 + c * 8];
    }
    __syncthreads();

    const int oc = n0 + w * 16 + nn;
    f16x8 af[4];
    #pragma unroll
    for (int ks = 0; ks < 4; ks++)
        af[ks] = *(const f16x8*)&W[(size_t)oc * 128 + ks * 32 + quad * 8];
    f32x4 acc[4] = {};
    #pragma unroll
    for (int ks = 0; ks < 4; ks++)
        #pragma unroll
        for (int nt = 0; nt < 4; nt++) {
            f16x8 bf = *(const f16x8*)&Alds[(nt * 16 + nn) * 136 + ks * 32 + quad * 8];
            acc[nt] = __builtin_amdgcn_mfma_f32_16x16x32_f16(af[ks], bf, acc[nt], 0, 0, 0);
        }
    float bv[4];
    #pragma unroll
    for (int r = 0; r < 4; r++) bv[r] = bias[n0 + w * 16 + quad * 4 + r];

    if (n0 < 256) {
        #pragma unroll
        for (int nt = 0; nt < 4; nt++) {
            int pos = m0 + nt * 16 + nn;
            PkU p0, p1;
            p0.h = __builtin_amdgcn_cvt_pkrtz(acc[nt][0] + bv[0], acc[nt][1] + bv[1]);
            p1.h = __builtin_amdgcn_cvt_pkrtz(acc[nt][2] + bv[2], acc[nt][3] + bv[3]);
            *(uint2*)&qkh[(size_t)pos * 256 + n0 + w * 16 + quad * 4] = make_uint2(p0.u, p1.u);
        }
    } else {
        #pragma unroll
        for (int nt = 0; nt < 4; nt++) {
            int pos = m0 + nt * 16 + nn;
            #pragma unroll
            for (int r = 0; r < 4; r++) {
                int chg = n0 - 256 + w * 16 + quad * 4 + r;
                vt[(size_t)chg * NPAD + pos] = (f16)(acc[nt][r] + bv[r]);
            }
        }
    }
    __syncthreads();   // LDS reuse safety
}

// ---------- stage: final projection (virtual 0..703), fp32 out ----------
__device__ __forceinline__ void out_v(int vb, int tid, char* smem,
    const f16* A, const f16* W, const float* bias, float* outp)
{
    f16* Alds = (f16*)smem;   // [64][136]
    const int m0 = (vb >> 1) * 64, n0 = (vb & 1) * 64;
    const int w = tid >> 6, lane = tid & 63, quad = lane >> 4, nn = lane & 15;

    for (int i = tid; i < 1024; i += 256) {
        int r = i >> 4, c = i & 15;
        *(uint4*)&Alds[r * 136 + c * 8] = *(const uint4*)&A[(size_t)(m0 + r) * 128 + c * 8];
    }
    __syncthreads();

    const int oc = n0 + w * 16 + nn;
    f16x8 af[4];
    #pragma unroll
    for (int ks = 0; ks < 4; ks++)
        af[ks] = *(const f16x8*)&W[(size_t)oc * 128 + ks * 32 + quad * 8];
    f32x4 acc[4] = {};
    #pragma unroll
    for (int ks = 0; ks < 4; ks++)
        #pragma unroll
        for (int nt = 0; nt < 4; nt++) {
            f16x8 bf = *(const f16x8*)&Alds[(nt * 16 + nn) * 136 + ks * 32 + quad * 8];
            acc[nt] = __builtin_amdgcn_mfma_f32_16x16x32_f16(af[ks], bf, acc[nt], 0, 0, 0);
        }
    float bv[4];
    #pragma unroll
    for (int r = 0; r < 4; r++) bv[r] = bias[n0 + w * 16 + quad * 4 + r];
    #pragma unroll
    for (int nt = 0; nt < 4; nt++) {
        int pos = m0 + nt * 16 + nn;
        f32x4 vv;
        #pragma unroll
        for (int r = 0; r < 4; r++) vv[r] = acc[nt][r] + bv[r];
        *(f32x4*)&outp[(size_t)pos * 128 + n0 + w * 16 + quad * 4] = vv;
    }
    __syncthreads();   // LDS reuse safety
}

// ---------- stage: attention (virtual 0..1407; two 128-thread halves per block) ----------
__device__ __forceinline__ void attn_v(int va, int tid256, char* lds,
    const f16* qkh, const f16* vt, const float* rpbp, f16* ao)
{
    const int half = tid256 >> 7;
    const int tid = tid256 & 127;
    char* base = lds + half * 14848;
    f16 (*Plds)[40] = (f16 (*)[40])base;              // [32][40]
    float (*Olds)[48] = (float (*)[48])(base + 2560); // [64][48]

    const int hh = va / 352;
    const int rr = va - hh * 352;
    const int i0 = (rr & 31) * 8;
    const int j0 = (rr >> 5) * 8;

    const int w = tid >> 6, lane = tid & 63;
    const int quad = lane >> 4, nn = lane & 15;

    const int ri0 = min(max(i0 - 12, 0), TT - 32);
    const int rj0 = min(max(j0 - 12, 0), PP - WIN) & ~1;

    int qi_[4], si_[4], dbb_[4];
    unsigned cm_[4];
    f16x8 qf[4];
    #pragma unroll
    for (int qs = 0; qs < 4; qs++) {
        int ql = qs * 16 + nn;
        int qi = i0 + (ql >> 3), qj = j0 + (ql & 7);
        int si = min(max(qi - 12, 0), TT - WIN);
        int sj = min(max(qj - 12, 0), PP - WIN);
        qi_[qs] = qi; si_[qs] = si;
        cm_[qs] = 0x1FFFFFFu << (sj - rj0);
        dbb_[qs] = rj0 - qj + 24;
        qf[qs] = *(const f16x8*)&qkh[(size_t)(qi * PP + qj) * 256 + hh * HD + quad * 8];
    }
    const float* rp_h = rpbp + hh * RPBSZ;
    const f16* vbase = vt + (size_t)(hh * HD + nn) * NPAD;
    const f16x8 onesv = {(f16)1.f, (f16)1.f, (f16)1.f, (f16)1.f,
                         (f16)1.f, (f16)1.f, (f16)1.f, (f16)1.f};

    f32x4 O[4][2] = {};
    f32x4 lacc[4] = {};

    const int b0 = min(rj0 + nn, PP - 1);
    const int b1 = min(rj0 + 16 + nn, PP - 1);
    const size_t koff = 128 + hh * HD + quad * 8;

    for (int c = 0; c < 16; c++) {
        int aa = ri0 + w * 16 + c;                          // in [0, 255]
        const f16* rowK = qkh + (size_t)aa * PP * 256 + koff;
        f16x8 kf0 = *(const f16x8*)(rowK + (size_t)b0 * 256);
        f16x8 kf1 = *(const f16x8*)(rowK + (size_t)b1 * 256);
        const f16* vrow = vbase + aa * PP + rj0 + quad * 8;
        f16x8 vf0 = *(const f16x8u*)vrow;
        f16x8 vf1 = *(const f16x8u*)(vrow + (size_t)16 * NPAD);

        #pragma unroll
        for (int qs = 0; qs < 4; qs++) {
            unsigned vm = ((unsigned)(aa - si_[qs]) <= 24u) ? cm_[qs] : 0u;
            const float* rp = rp_h + (aa - qi_[qs] + 24) * RPBW + dbb_[qs];
            f32x4 ra = *(const f32x4u*)(rp + quad * 4);
            f32x4 rb = *(const f32x4u*)(rp + 16 + quad * 4);
            f32x4 za, zb;
            #pragma unroll
            for (int r = 0; r < 4; r++) {
                int kl0 = quad * 4 + r;
                za[r] = ((vm >> kl0) & 1u) ? ra[r] : -1e30f;
                zb[r] = ((vm >> (kl0 + 16)) & 1u) ? rb[r] : -1e30f;
            }
            f32x4 s0 = __builtin_amdgcn_mfma_f32_16x16x32_f16(kf0, qf[qs], za, 0, 0, 0);
            f32x4 s1 = __builtin_amdgcn_mfma_f32_16x16x32_f16(kf1, qf[qs], zb, 0, 0, 0);

            float p[8];
            #pragma unroll
            for (int r = 0; r < 4; r++) {
                p[r]     = EXP2(s0[r]);
                p[r + 4] = EXP2(s1[r]);
            }
            PkU a, b, cc, d;
            a.h  = __builtin_amdgcn_cvt_pkrtz(p[0], p[1]);
            b.h  = __builtin_amdgcn_cvt_pkrtz(p[2], p[3]);
            cc.h = __builtin_amdgcn_cvt_pkrtz(p[4], p[5]);
            d.h  = __builtin_amdgcn_cvt_pkrtz(p[6], p[7]);
            *(uint2*)&Plds[w * 16 + nn][quad * 4]      = make_uint2(a.u, b.u);
            *(uint2*)&Plds[w * 16 + nn][16 + quad * 4] = make_uint2(cc.u, d.u);
            f16x8 pf = *(const f16x8*)&Plds[w * 16 + nn][quad * 8];

            O[qs][0] = __builtin_amdgcn_mfma_f32_16x16x32_f16(pf, vf0, O[qs][0], 0, 0, 0);
            O[qs][1] = __builtin_amdgcn_mfma_f32_16x16x32_f16(pf, vf1, O[qs][1], 0, 0, 0);
            lacc[qs] = __builtin_amdgcn_mfma_f32_16x16x32_f16(pf, onesv, lacc[qs], 0, 0, 0);
        }
    }

    __syncthreads();   // both halves aligned; previous Olds reads complete
    if (w == 1) {
        float* ob = Olds[lane];
        #pragma unroll
        for (int qs = 0; qs < 4; qs++) {
            *(f32x4*)&ob[qs * 12]     = O[qs][0];
            *(f32x4*)&ob[qs * 12 + 4] = O[qs][1];
            *(f32x4*)&ob[qs * 12 + 8] = lacc[qs];
        }
    }
    __syncthreads();
    if (w == 0) {
        const float* ob = Olds[lane];
        #pragma unroll
        for (int qs = 0; qs < 4; qs++) {
            O[qs][0] += *(const f32x4*)&ob[qs * 12];
            O[qs][1] += *(const f32x4*)&ob[qs * 12 + 4];
            lacc[qs] += *(const f32x4*)&ob[qs * 12 + 8];
            #pragma unroll
            for (int r = 0; r < 4; r++) {
                float li = 1.f / lacc[qs][r];
                int ql = qs * 16 + quad * 4 + r;
                int qi = i0 + (ql >> 3), qj = j0 + (ql & 7);
                size_t ob2 = (size_t)(qi * PP + qj) * CC + hh * HD;
                ao[ob2 + nn]      = (f16)(O[qs][0][r] * li);
                ao[ob2 + 16 + nn] = (f16)(O[qs][1][r] * li);
            }
        }
    }
}

// ---------- cooperative mega-kernel: min 2 blocks/CU guaranteed -> grid 512 valid ----------
__global__ __launch_bounds__(256, 2) void mega(
    const float* __restrict__ x, const float* __restrict__ cond, const float* __restrict__ mask,
    const float* __restrict__ lw, const float* __restrict__ lb,
    const float* __restrict__ qw, const float* __restrict__ qb,
    const float* __restrict__ rpb, const float* __restrict__ pw, const float* __restrict__ pbias,
    float* __restrict__ outp,
    float* qbs, float* b2s, float* rpbp,
    f16* qwh, f16* pwh, f16* w2h, f16* yh, f16* qkh, f16* vt, f16* ao)
{
    __shared__ __align__(16) char smem[SMEM_BYTES];
    cg::grid_group grid = cg::this_grid();
    const int tid = threadIdx.x;
    const int pbk = blockIdx.x;
    const int nb = gridDim.x;

    for (int vb = pbk; vb < 932; vb += nb) {
        if (vb < 228) prep_v(vb, tid, qw, pw, qb, pbias, rpb, qwh, pwh, w2h, qbs, b2s, rpbp);
        else fusion_v(vb - 228, tid, smem, x, cond, mask, lw, lb, yh);
    }
    grid.sync();
    for (int vb = pbk; vb < 2112; vb += nb) qkv_v(vb, tid, smem, yh, qwh, qbs, qkh, vt);
    grid.sync();
    for (int t = pbk; t < 704; t += nb) attn_v(t * 2 + (tid >> 7), tid, smem, qkh, vt, rpbp, ao);
    grid.sync();
    for (int vb = pbk; vb < 2112; vb += nb) qkv_v(vb, tid, smem, ao, w2h, b2s, qkh, vt);
    grid.sync();
    for (int t = pbk; t < 704; t += nb) attn_v(t * 2 + (tid >> 7), tid, smem, qkh, vt, rpbp, ao);
    grid.sync();
    for (int vb = pbk; vb < 704; vb += nb) out_v(vb, tid, smem, ao, pwh, pbias, outp);
}

// ---------- fallback wrappers (R12-equivalent chain from the same stage functions) ----------
__global__ __launch_bounds__(256) void k_prep(
    const float* qw, const float* pw, const float* qb, const float* pbias, const float* rpb,
    f16* qwh, f16* pwh, f16* w2h, float* qbs, float* b2s, float* rpbp) {
    prep_v(blockIdx.x, threadIdx.x, qw, pw, qb, pbias, rpb, qwh, pwh, w2h, qbs, b2s, rpbp);
}
__global__ __launch_bounds__(256) void k_fusion(
    const float* x, const float* cond, const float* mask,
    const float* lw, const float* lb, f16* yh) {
    __shared__ __align__(16) char smem[21504];
    fusion_v(blockIdx.x, threadIdx.x, smem, x, cond, mask, lw, lb, yh);
}
__global__ __launch_bounds__(256) void k_qkv(
    const f16* A, const f16* W, const float* bias, f16* qkh, f16* vt) {
    __shared__ __align__(16) char smem[17408];
    qkv_v(blockIdx.x, threadIdx.x, smem, A, W, bias, qkh, vt);
}
__global__ __launch_bounds__(256) void k_attn(
    const f16* qkh, const f16* vt, const float* rpbp, f16* ao) {
    __shared__ __align__(16) char smem[SMEM_BYTES];
    attn_v(blockIdx.x * 2 + (threadIdx.x >> 7), threadIdx.x, smem, qkh, vt, rpbp, ao);
}
__global__ __launch_bounds__(256) void k_out(
    const f16* A, const f16* W, const float* bias, float* outp) {
    __shared__ __align__(16) char smem[17408];
    out_v(blockIdx.x, threadIdx.x, smem, A, W, bias, outp);
}

extern "C" void kernel_launch(void* const* d_in, const int* in_sizes, int n_in,
                              void* d_out, int out_size, void* d_ws, size_t ws_size,
                              hipStream_t stream) {
    (void)in_sizes; (void)n_in; (void)out_size; (void)ws_size;
    const float* x    = (const float*)d_in[0];
    const float* cond = (const float*)d_in[1];
    const float* mask = (const float*)d_in[2];
    const float* lw   = (const float*)d_in[3];
    const float* lb   = (const float*)d_in[4];
    const float* qw   = (const float*)d_in[5];
    const float* qb   = (const float*)d_in[6];
    const float* rpb  = (const float*)d_in[7];
    const float* pw   = (const float*)d_in[8];
    const float* pbias = (const float*)d_in[9];
    float* outp       = (float*)d_out;

    float* ws   = (float*)d_ws;
    float* qbs  = ws;                             // 384
    float* b2s  = qbs + 384;                      // 384
    float* rpbp = b2s + 384;                      // 10240 padded
    f16* qwh  = (f16*)(rpbp + 10240);             // 384*128
    f16* pwh  = qwh + 49152;                      // 128*128
    f16* w2h  = pwh + 16384;                      // 384*128
    f16* yh   = w2h + 49152;                      // NN*128
    f16* qkh  = yh + (size_t)NN * 128;            // NN*256 (Q|K)
    f16* vt   = qkh + (size_t)NN * 256;           // 128*NPAD
    f16* ao   = vt + (size_t)128 * NPAD;          // NN*128

    // try the cooperative mega-kernel; 512 blocks = 2/CU, guaranteed by launch_bounds(256,2)
    void* args[] = {
        (void*)&x, (void*)&cond, (void*)&mask, (void*)&lw, (void*)&lb,
        (void*)&qw, (void*)&qb, (void*)&rpb, (void*)&pw, (void*)&pbias,
        (void*)&outp, (void*)&qbs, (void*)&b2s, (void*)&rpbp,
        (void*)&qwh, (void*)&pwh, (void*)&w2h, (void*)&yh, (void*)&qkh,
        (void*)&vt, (void*)&ao
    };
    hipError_t err = hipLaunchCooperativeKernel((const void*)mega, dim3(512), dim3(256),
                                                args, 0, stream);
    if (err != hipSuccess) {
        // fallback: verified multi-kernel chain (same device code, thin wrappers)
        k_prep<<<228, 256, 0, stream>>>(qw, pw, qb, pbias, rpb, qwh, pwh, w2h, qbs, b2s, rpbp);
        k_fusion<<<704, 256, 0, stream>>>(x, cond, mask, lw, lb, yh);
        k_qkv<<<2112, 256, 0, stream>>>(yh, qwh, qbs, qkh, vt);
        k_attn<<<704, 256, 0, stream>>>(qkh, vt, rpbp, ao);
        k_qkv<<<2112, 256, 0, stream>>>(ao, w2h, b2s, qkh, vt);
        k_attn<<<704, 256, 0, stream>>>(qkh, vt, rpbp, ao);
        k_out<<<704, 256, 0, stream>>>(ao, pwh, pbias, outp);
    }
}

// Round 16
// 265.059 us; speedup vs baseline: 2.5824x; 2.2052x over previous
//
#include <hip/hip_runtime.h>
#include <hip/hip_fp16.h>

#define TT 256
#define PP 88
#define CC 128
#define NN (TT * PP)          // 22528 positions
#define NPAD (NN + 32)
#define HEADS 4
#define HD 32
#define WIN 25
#define RPBW 49
#define RPBSZ (RPBW * RPBW)   // 2401
#define SCALE 0.17677669529663687f   // 1/sqrt(32)
#define LOG2E 1.4426950408889634f
#define QSC (SCALE * LOG2E)          // fold exp->exp2 into Q path

#if __has_builtin(__builtin_amdgcn_exp2f)
#define EXP2(x) __builtin_amdgcn_exp2f(x)
#else
#define EXP2(x) exp2f(x)
#endif

typedef _Float16 f16;
typedef f16 f16x8 __attribute__((ext_vector_type(8)));
typedef f16 f16x8u __attribute__((ext_vector_type(8), aligned(4)));
typedef float f32x4 __attribute__((ext_vector_type(4)));
typedef float f32x4u __attribute__((ext_vector_type(4), aligned(4)));
typedef __fp16 hf16x2 __attribute__((ext_vector_type(2)));
union PkU { hf16x2 h; unsigned u; };

// ---------- prep: repack (b<192) + parallel b2s (192<=b<216) + MFMA wcomb (216<=b<228) ----------
__global__ __launch_bounds__(256) void prep(
    const float* __restrict__ lw, const float* __restrict__ qw,
    const float* __restrict__ pw, const float* __restrict__ qb,
    const float* __restrict__ pb, const float* __restrict__ rpb,
    f16* __restrict__ lwh, f16* __restrict__ qwh, f16* __restrict__ pwh,
    f16* __restrict__ w2h, float* __restrict__ qbs, float* __restrict__ b2s,
    float* __restrict__ rpbp)
{
    const int b = blockIdx.x;
    if (b < 192) {
        int idx = b * 256 + threadIdx.x;              // covers 49152
        if (idx < 128 * 160) {                        // fusion W: [128][131] -> [128][160] pad
            int r = idx / 160, c = idx - r * 160;
            lwh[idx] = (f16)(c < 131 ? lw[r * 131 + c] : 0.f);
        }
        if (idx < 384 * 128) {                        // qkv W, Q rows scaled by QSC
            float v = qw[idx];
            if (idx < 128 * 128) v *= QSC;
            qwh[idx] = (f16)v;
        }
        if (idx < 128 * 128) pwh[idx] = (f16)pw[idx];
        if (idx < 384) qbs[idx] = qb[idx] * (idx < 128 ? QSC : 1.f);
        if (idx < 10240) rpbp[idx] = (idx < 4 * RPBSZ) ? rpb[idx] * LOG2E : 0.f;
    } else if (b < 216) {
        // b2s[i] = (qb[i] + qw[i,:]·pb) * sc_i ; 16 lanes per output, shuffle-reduce
        int t = (b - 192) * 256 + threadIdx.x;        // [0, 6144)
        int i = t >> 4, l = t & 15;
        if (i < 384) {
            float s = 0.f;
            #pragma unroll
            for (int j = l * 8; j < l * 8 + 8; j++) s += qw[i * 128 + j] * pb[j];
            s += __shfl_xor(s, 1); s += __shfl_xor(s, 2);
            s += __shfl_xor(s, 4); s += __shfl_xor(s, 8);
            if (l == 0) b2s[i] = (qb[i] + s) * (i < 128 ? QSC : 1.f);
        }
    } else {
        // w2h[i][k] = sc_i * sum_j qw[i][j] pw[j][k]
        const int bw = b - 216;                       // 0..11
        const int m0 = (bw & 1) * 64;                 // k-tile
        const int n0 = (bw >> 1) * 64;                // i-tile
        const int tid = threadIdx.x;
        const int w = tid >> 6, lane = tid & 63, quad = lane >> 4, nn = lane & 15;
        const int krow = m0 + w * 16 + nn;
        f16x8 af[4];
        #pragma unroll
        for (int ks = 0; ks < 4; ks++) {
            union { f16 e[8]; f16x8 v; } t;
            #pragma unroll
            for (int e = 0; e < 8; e++)
                t.e[e] = (f16)pw[(ks * 32 + quad * 8 + e) * 128 + krow];
            af[ks] = t.v;
        }
        f32x4 acc[4] = {};
        #pragma unroll
        for (int nt = 0; nt < 4; nt++) {
            int irow = n0 + nt * 16 + nn;
            #pragma unroll
            for (int ks = 0; ks < 4; ks++) {
                const float* qr = &qw[(size_t)irow * 128 + ks * 32 + quad * 8];
                float4 a = *(const float4*)qr, bq = *(const float4*)(qr + 4);
                PkU u0, u1, u2, u3;
                u0.h = __builtin_amdgcn_cvt_pkrtz(a.x, a.y);
                u1.h = __builtin_amdgcn_cvt_pkrtz(a.z, a.w);
                u2.h = __builtin_amdgcn_cvt_pkrtz(bq.x, bq.y);
                u3.h = __builtin_amdgcn_cvt_pkrtz(bq.z, bq.w);
                union { unsigned u[4]; f16x8 v; } bb;
                bb.u[0] = u0.u; bb.u[1] = u1.u; bb.u[2] = u2.u; bb.u[3] = u3.u;
                acc[nt] = __builtin_amdgcn_mfma_f32_16x16x32_f16(af[ks], bb.v, acc[nt], 0, 0, 0);
            }
        }
        #pragma unroll
        for (int nt = 0; nt < 4; nt++) {
            int i = n0 + nt * 16 + nn;
            float sc = (i < 128) ? QSC : 1.f;
            PkU p0, p1;
            p0.h = __builtin_amdgcn_cvt_pkrtz(acc[nt][0] * sc, acc[nt][1] * sc);
            p1.h = __builtin_amdgcn_cvt_pkrtz(acc[nt][2] * sc, acc[nt][3] * sc);
            *(uint2*)&w2h[(size_t)i * 128 + m0 + w * 16 + quad * 4] = make_uint2(p0.u, p1.u);
        }
    }
}

// ---------- fusion GEMM: yh = relu(cat @ lwh^T + lb); grid (352, 2) ----------
__global__ __launch_bounds__(256) void fusion_gemm(
    const float* __restrict__ x, const float* __restrict__ cond, const float* __restrict__ mask,
    const f16* __restrict__ lwh, const float* __restrict__ lb, f16* __restrict__ yh)
{
    __shared__ __align__(16) f16 Alds[64 * 168];
    const int m0 = blockIdx.x * 64, n0 = blockIdx.y * 64;
    const int tid = threadIdx.x;
    const int w = tid >> 6, lane = tid & 63, quad = lane >> 4, nn = lane & 15;

    {   // stage cat rows (f16)
        int r = tid >> 2, cpart = tid & 3;
        size_t pos = m0 + r;
        *(uint4*)&Alds[r * 168 + 128 + cpart * 8] = make_uint4(0, 0, 0, 0);
        const float* xr = x + pos * 128 + cpart * 32;
        #pragma unroll
        for (int t = 0; t < 4; t++) {
            float4 a = *(const float4*)(xr + t * 8);
            float4 b = *(const float4*)(xr + t * 8 + 4);
            PkU p0, p1, p2, p3;
            p0.h = __builtin_amdgcn_cvt_pkrtz(a.x, a.y);
            p1.h = __builtin_amdgcn_cvt_pkrtz(a.z, a.w);
            p2.h = __builtin_amdgcn_cvt_pkrtz(b.x, b.y);
            p3.h = __builtin_amdgcn_cvt_pkrtz(b.z, b.w);
            *(uint4*)&Alds[r * 168 + cpart * 32 + t * 8] = make_uint4(p0.u, p1.u, p2.u, p3.u);
        }
        if (cpart == 0) {
            Alds[r * 168 + 128] = (f16)cond[pos * 2];
            Alds[r * 168 + 129] = (f16)cond[pos * 2 + 1];
            Alds[r * 168 + 130] = (f16)mask[pos];
        }
    }
    __syncthreads();

    const int oc = n0 + w * 16 + nn;
    f16x8 af[5];
    #pragma unroll
    for (int ks = 0; ks < 5; ks++)
        af[ks] = *(const f16x8*)&lwh[(size_t)oc * 160 + ks * 32 + quad * 8];
    f32x4 acc[4] = {};
    #pragma unroll
    for (int ks = 0; ks < 5; ks++)
        #pragma unroll
        for (int nt = 0; nt < 4; nt++) {
            f16x8 bf = *(const f16x8*)&Alds[(nt * 16 + nn) * 168 + ks * 32 + quad * 8];
            acc[nt] = __builtin_amdgcn_mfma_f32_16x16x32_f16(af[ks], bf, acc[nt], 0, 0, 0);
        }
    float bv[4];
    #pragma unroll
    for (int r = 0; r < 4; r++) bv[r] = lb[n0 + w * 16 + quad * 4 + r];
    #pragma unroll
    for (int nt = 0; nt < 4; nt++) {
        int pos = m0 + nt * 16 + nn;
        PkU p0, p1;
        p0.h = __builtin_amdgcn_cvt_pkrtz(fmaxf(acc[nt][0] + bv[0], 0.f), fmaxf(acc[nt][1] + bv[1], 0.f));
        p1.h = __builtin_amdgcn_cvt_pkrtz(fmaxf(acc[nt][2] + bv[2], 0.f), fmaxf(acc[nt][3] + bv[3], 0.f));
        *(uint2*)&yh[(size_t)pos * 128 + n0 + w * 16 + quad * 4] = make_uint2(p0.u, p1.u);
    }
}

// ---------- qkv GEMM: grid (352, 6); Q|K rows stride 256, V transposed ----------
__global__ __launch_bounds__(256) void gemm_qkv(
    const f16* __restrict__ A, const f16* __restrict__ W, const float* __restrict__ bias,
    f16* __restrict__ qkh, f16* __restrict__ vt)
{
    __shared__ __align__(16) f16 Alds[64 * 136];
    const int m0 = blockIdx.x * 64, n0 = blockIdx.y * 64;
    const int tid = threadIdx.x;
    const int w = tid >> 6, lane = tid & 63, quad = lane >> 4, nn = lane & 15;

    for (int i = tid; i < 1024; i += 256) {
        int r = i >> 4, c = i & 15;
        *(uint4*)&Alds[r * 136 + c * 8] = *(const uint4*)&A[(size_t)(m0 + r) * 128 + c * 8];
    }
    __syncthreads();

    const int oc = n0 + w * 16 + nn;
    f16x8 af[4];
    #pragma unroll
    for (int ks = 0; ks < 4; ks++)
        af[ks] = *(const f16x8*)&W[(size_t)oc * 128 + ks * 32 + quad * 8];
    f32x4 acc[4] = {};
    #pragma unroll
    for (int ks = 0; ks < 4; ks++)
        #pragma unroll
        for (int nt = 0; nt < 4; nt++) {
            f16x8 bf = *(const f16x8*)&Alds[(nt * 16 + nn) * 136 + ks * 32 + quad * 8];
            acc[nt] = __builtin_amdgcn_mfma_f32_16x16x32_f16(af[ks], bf, acc[nt], 0, 0, 0);
        }
    float bv[4];
    #pragma unroll
    for (int r = 0; r < 4; r++) bv[r] = bias[n0 + w * 16 + quad * 4 + r];

    if (n0 < 256) {
        #pragma unroll
        for (int nt = 0; nt < 4; nt++) {
            int pos = m0 + nt * 16 + nn;
            PkU p0, p1;
            p0.h = __builtin_amdgcn_cvt_pkrtz(acc[nt][0] + bv[0], acc[nt][1] + bv[1]);
            p1.h = __builtin_amdgcn_cvt_pkrtz(acc[nt][2] + bv[2], acc[nt][3] + bv[3]);
            *(uint2*)&qkh[(size_t)pos * 256 + n0 + w * 16 + quad * 4] = make_uint2(p0.u, p1.u);
        }
    } else {
        #pragma unroll
        for (int nt = 0; nt < 4; nt++) {
            int pos = m0 + nt * 16 + nn;
            #pragma unroll
            for (int r = 0; r < 4; r++) {
                int chg = n0 - 256 + w * 16 + quad * 4 + r;
                vt[(size_t)chg * NPAD + pos] = (f16)(acc[nt][r] + bv[r]);
            }
        }
    }
}

// ---------- final projection: grid (352, 2), fp32 out ----------
__global__ __launch_bounds__(256) void gemm_out(
    const f16* __restrict__ A, const f16* __restrict__ W, const float* __restrict__ bias,
    float* __restrict__ outp)
{
    __shared__ __align__(16) f16 Alds[64 * 136];
    const int m0 = blockIdx.x * 64, n0 = blockIdx.y * 64;
    const int tid = threadIdx.x;
    const int w = tid >> 6, lane = tid & 63, quad = lane >> 4, nn = lane & 15;

    for (int i = tid; i < 1024; i += 256) {
        int r = i >> 4, c = i & 15;
        *(uint4*)&Alds[r * 136 + c * 8] = *(const uint4*)&A[(size_t)(m0 + r) * 128 + c * 8];
    }
    __syncthreads();

    const int oc = n0 + w * 16 + nn;
    f16x8 af[4];
    #pragma unroll
    for (int ks = 0; ks < 4; ks++)
        af[ks] = *(const f16x8*)&W[(size_t)oc * 128 + ks * 32 + quad * 8];
    f32x4 acc[4] = {};
    #pragma unroll
    for (int ks = 0; ks < 4; ks++)
        #pragma unroll
        for (int nt = 0; nt < 4; nt++) {
            f16x8 bf = *(const f16x8*)&Alds[(nt * 16 + nn) * 136 + ks * 32 + quad * 8];
            acc[nt] = __builtin_amdgcn_mfma_f32_16x16x32_f16(af[ks], bf, acc[nt], 0, 0, 0);
        }
    float bv[4];
    #pragma unroll
    for (int r = 0; r < 4; r++) bv[r] = bias[n0 + w * 16 + quad * 4 + r];
    #pragma unroll
    for (int nt = 0; nt < 4; nt++) {
        int pos = m0 + nt * 16 + nn;
        f32x4 vv;
        #pragma unroll
        for (int r = 0; r < 4; r++) vv[r] = acc[nt][r] + bv[r];
        *(f32x4*)&outp[(size_t)pos * 128 + n0 + w * 16 + quad * 4] = vv;
    }
}

// ---------- MFMA neighborhood attention: 8x8 query tile, 2 waves key-split, pipelined ----------
// R12 body + (a) wave-uniform per-qset chunk skip (rows outside [lo,hi] contribute
// nothing: 5 MFMA + 8 exp2 + P round-trip elided, ~16% of chunk-qsets), (b) Olds
// stride 49 (odd*4B) to kill the 16-way merge bank conflicts of stride 48.
__global__ __launch_bounds__(128) void attn_mfma(
    const f16* __restrict__ qkh,   // [N][256] = Q|K, Q pre-scaled by QSC
    const f16* __restrict__ vt,    // [128][NPAD]
    const float* __restrict__ rpbp,
    f16* __restrict__ ao)          // [N][128]
{
    const int i0 = blockIdx.x * 8;
    const int j0 = blockIdx.y * 8;
    const int h  = blockIdx.z;
    const int tid = threadIdx.x;
    const int w = tid >> 6, lane = tid & 63;
    const int quad = lane >> 4, nn = lane & 15;

    const int ri0 = min(max(i0 - 12, 0), TT - 32);
    const int rj0 = min(max(j0 - 12, 0), PP - WIN) & ~1;

    __shared__ f16 Plds[2][16][40];
    __shared__ __align__(16) float Olds[64][49];   // stride 49 floats: odd*4B -> conflict-free

    int qi_[4], si_[4], dbb_[4], lo_[4], hi_[4];
    unsigned cm_[4];
    f16x8 qf[4];
    #pragma unroll
    for (int qs = 0; qs < 4; qs++) {
        int ql = qs * 16 + nn;
        int qi = i0 + (ql >> 3), qj = j0 + (ql & 7);
        int si = min(max(qi - 12, 0), TT - WIN);
        int sj = min(max(qj - 12, 0), PP - WIN);
        qi_[qs] = qi; si_[qs] = si;
        cm_[qs] = 0x1FFFFFFu << (sj - rj0);       // shift <= 7
        dbb_[qs] = rj0 - qj + 24;
        qf[qs] = *(const f16x8*)&qkh[(size_t)(qi * PP + qj) * 256 + h * HD + quad * 8];
        // block-uniform valid row range for this qset (2 query rows: i0+qs*2, +1)
        lo_[qs] = min(max(i0 + qs * 2 - 12, 0), TT - WIN);
        hi_[qs] = min(max(i0 + qs * 2 + 1 - 12, 0), TT - WIN) + 24;
    }
    const float* rp_h = rpbp + h * RPBSZ;
    const f16* vbase = vt + (size_t)(h * HD + nn) * NPAD;
    const f16x8 onesv = {(f16)1.f, (f16)1.f, (f16)1.f, (f16)1.f,
                         (f16)1.f, (f16)1.f, (f16)1.f, (f16)1.f};

    f32x4 O[4][2] = {};    // [qset][ch-half]; regs = queries, lane nn = channel
    f32x4 lacc[4] = {};    // regs = queries

    const int b0 = min(rj0 + nn, PP - 1);
    const int b1 = min(rj0 + 16 + nn, PP - 1);
    const size_t koff = 128 + h * HD + quad * 8;

    // prologue: load chunk w*16
    int aa = ri0 + w * 16;
    const f16* rowK = qkh + (size_t)aa * PP * 256 + koff;
    f16x8 kf0 = *(const f16x8*)(rowK + (size_t)b0 * 256);
    f16x8 kf1 = *(const f16x8*)(rowK + (size_t)b1 * 256);
    const f16* vrow = vbase + aa * PP + rj0 + quad * 8;
    f16x8 vf0 = *(const f16x8u*)vrow;
    f16x8 vf1 = *(const f16x8u*)(vrow + (size_t)16 * NPAD);

    for (int c = 0; c < 16; c++) {
        // prefetch chunk aa+1 (last iteration overshoots into vt/ao scratch: unused)
        const f16* rowKn = qkh + (size_t)(aa + 1) * PP * 256 + koff;
        f16x8 nkf0 = *(const f16x8*)(rowKn + (size_t)b0 * 256);
        f16x8 nkf1 = *(const f16x8*)(rowKn + (size_t)b1 * 256);
        const f16* vrown = vbase + (aa + 1) * PP + rj0 + quad * 8;
        f16x8 nvf0 = *(const f16x8u*)vrown;
        f16x8 nvf1 = *(const f16x8u*)(vrown + (size_t)16 * NPAD);

        #pragma unroll
        for (int qs = 0; qs < 4; qs++) {
            if (aa < lo_[qs] || aa > hi_[qs]) continue;   // wave-uniform: whole row invalid
            unsigned vm = ((unsigned)(aa - si_[qs]) <= 24u) ? cm_[qs] : 0u;
            const float* rp = rp_h + (aa - qi_[qs] + 24) * RPBW + dbb_[qs];
            f32x4 ra = *(const f32x4u*)(rp + quad * 4);
            f32x4 rb = *(const f32x4u*)(rp + 16 + quad * 4);
            f32x4 za, zb;
            #pragma unroll
            for (int r = 0; r < 4; r++) {
                int kl0 = quad * 4 + r;
                za[r] = ((vm >> kl0) & 1u) ? ra[r] : -1e30f;
                zb[r] = ((vm >> (kl0 + 16)) & 1u) ? rb[r] : -1e30f;
            }
            f32x4 s0 = __builtin_amdgcn_mfma_f32_16x16x32_f16(kf0, qf[qs], za, 0, 0, 0);
            f32x4 s1 = __builtin_amdgcn_mfma_f32_16x16x32_f16(kf1, qf[qs], zb, 0, 0, 0);

            float p[8];
            #pragma unroll
            for (int r = 0; r < 4; r++) {
                p[r]     = EXP2(s0[r]);
                p[r + 4] = EXP2(s1[r]);
            }
            PkU a, b, cc, d;
            a.h  = __builtin_amdgcn_cvt_pkrtz(p[0], p[1]);
            b.h  = __builtin_amdgcn_cvt_pkrtz(p[2], p[3]);
            cc.h = __builtin_amdgcn_cvt_pkrtz(p[4], p[5]);
            d.h  = __builtin_amdgcn_cvt_pkrtz(p[6], p[7]);
            *(uint2*)&Plds[w][nn][quad * 4]      = make_uint2(a.u, b.u);
            *(uint2*)&Plds[w][nn][16 + quad * 4] = make_uint2(cc.u, d.u);
            f16x8 pf = *(const f16x8*)&Plds[w][nn][quad * 8];

            O[qs][0] = __builtin_amdgcn_mfma_f32_16x16x32_f16(pf, vf0, O[qs][0], 0, 0, 0);
            O[qs][1] = __builtin_amdgcn_mfma_f32_16x16x32_f16(pf, vf1, O[qs][1], 0, 0, 0);
            lacc[qs] = __builtin_amdgcn_mfma_f32_16x16x32_f16(pf, onesv, lacc[qs], 0, 0, 0);
        }
        kf0 = nkf0; kf1 = nkf1; vf0 = nvf0; vf1 = nvf1;
        aa++;
    }

    // ---- merge: wave1 stores partials, wave0 adds and finishes ----
    if (w == 1) {
        float* ob = Olds[lane];
        #pragma unroll
        for (int qs = 0; qs < 4; qs++) {
            *(f32x4u*)&ob[qs * 12]     = O[qs][0];
            *(f32x4u*)&ob[qs * 12 + 4] = O[qs][1];
            *(f32x4u*)&ob[qs * 12 + 8] = lacc[qs];
        }
    }
    __syncthreads();
    if (w == 0) {
        const float* ob = Olds[lane];
        #pragma unroll
        for (int qs = 0; qs < 4; qs++) {
            O[qs][0] += *(const f32x4u*)&ob[qs * 12];
            O[qs][1] += *(const f32x4u*)&ob[qs * 12 + 4];
            lacc[qs] += *(const f32x4u*)&ob[qs * 12 + 8];
            #pragma unroll
            for (int r = 0; r < 4; r++) {
                float li = 1.f / lacc[qs][r];
                int ql = qs * 16 + quad * 4 + r;
                int qi = i0 + (ql >> 3), qj = j0 + (ql & 7);
                size_t base = (size_t)(qi * PP + qj) * CC + h * HD;
                ao[base + nn]      = (f16)(O[qs][0][r] * li);
                ao[base + 16 + nn] = (f16)(O[qs][1][r] * li);
            }
        }
    }
}

extern "C" void kernel_launch(void* const* d_in, const int* in_sizes, int n_in,
                              void* d_out, int out_size, void* d_ws, size_t ws_size,
                              hipStream_t stream) {
    (void)in_sizes; (void)n_in; (void)out_size; (void)ws_size;
    const float* x    = (const float*)d_in[0];
    const float* cond = (const float*)d_in[1];
    const float* mask = (const float*)d_in[2];
    const float* lw   = (const float*)d_in[3];
    const float* lb   = (const float*)d_in[4];
    const float* qw   = (const float*)d_in[5];
    const float* qb   = (const float*)d_in[6];
    const float* rpb  = (const float*)d_in[7];
    const float* pw   = (const float*)d_in[8];
    const float* pb   = (const float*)d_in[9];
    float* outp       = (float*)d_out;

    float* ws   = (float*)d_ws;
    float* qbs  = ws;                 // 384
    float* b2s  = qbs + 384;          // 384
    float* rpbp = b2s + 384;          // 10240 padded
    f16* lwh  = (f16*)(rpbp + 10240);             // 128*160
    f16* qwh  = lwh + 20480;                      // 384*128
    f16* pwh  = qwh + 49152;                      // 128*128
    f16* w2h  = pwh + 16384;                      // 384*128
    f16* yh   = w2h + 49152;                      // NN*128
    f16* qkh  = yh + (size_t)NN * 128;            // NN*256 (Q|K)
    f16* vt   = qkh + (size_t)NN * 256;           // 128*NPAD
    f16* ao   = vt + (size_t)128 * NPAD;          // NN*128  (prefetch overshoot lands in vt/ao)

    prep<<<228, 256, 0, stream>>>(lw, qw, pw, qb, pb, rpb, lwh, qwh, pwh, w2h, qbs, b2s, rpbp);
    fusion_gemm<<<dim3(352, 2), 256, 0, stream>>>(x, cond, mask, lwh, lb, yh);
    gemm_qkv<<<dim3(352, 6), 256, 0, stream>>>(yh, qwh, qbs, qkh, vt);
    attn_mfma<<<dim3(TT / 8, PP / 8, HEADS), 128, 0, stream>>>(qkh, vt, rpbp, ao);
    gemm_qkv<<<dim3(352, 6), 256, 0, stream>>>(ao, w2h, b2s, qkh, vt);   // fused proj+qkv
    attn_mfma<<<dim3(TT / 8, PP / 8, HEADS), 128, 0, stream>>>(qkh, vt, rpbp, ao);
    gemm_out<<<dim3(352, 2), 256, 0, stream>>>(ao, pwh, pb, outp);
}

// Round 17
// 222.341 us; speedup vs baseline: 3.0785x; 1.1921x over previous
//
#include <hip/hip_runtime.h>
#include <hip/hip_fp16.h>

#define TT 256
#define PP 88
#define CC 128
#define NN (TT * PP)          // 22528 positions
#define NPAD (NN + 32)
#define HEADS 4
#define HD 32
#define WIN 25
#define RPBW 49
#define RPBSZ (RPBW * RPBW)   // 2401
#define SCALE 0.17677669529663687f   // 1/sqrt(32)
#define LOG2E 1.4426950408889634f
#define QSC (SCALE * LOG2E)          // fold exp->exp2 into Q path

#if __has_builtin(__builtin_amdgcn_exp2f)
#define EXP2(x) __builtin_amdgcn_exp2f(x)
#else
#define EXP2(x) exp2f(x)
#endif

typedef _Float16 f16;
typedef f16 f16x8 __attribute__((ext_vector_type(8)));
typedef f16 f16x8u __attribute__((ext_vector_type(8), aligned(4)));
typedef float f32x4 __attribute__((ext_vector_type(4)));
typedef float f32x4u __attribute__((ext_vector_type(4), aligned(4)));
typedef __fp16 hf16x2 __attribute__((ext_vector_type(2)));
union PkU { hf16x2 h; unsigned u; };

// ---------- prep: repack (b<192) + parallel b2s (192<=b<216) + MFMA wcomb (216<=b<228) ----------
__global__ __launch_bounds__(256) void prep(
    const float* __restrict__ lw, const float* __restrict__ qw,
    const float* __restrict__ pw, const float* __restrict__ qb,
    const float* __restrict__ pb, const float* __restrict__ rpb,
    f16* __restrict__ lwh, f16* __restrict__ qwh, f16* __restrict__ pwh,
    f16* __restrict__ w2h, float* __restrict__ qbs, float* __restrict__ b2s,
    float* __restrict__ rpbp)
{
    const int b = blockIdx.x;
    if (b < 192) {
        int idx = b * 256 + threadIdx.x;              // covers 49152
        if (idx < 128 * 160) {                        // fusion W: [128][131] -> [128][160] pad
            int r = idx / 160, c = idx - r * 160;
            lwh[idx] = (f16)(c < 131 ? lw[r * 131 + c] : 0.f);
        }
        if (idx < 384 * 128) {                        // qkv W, Q rows scaled by QSC
            float v = qw[idx];
            if (idx < 128 * 128) v *= QSC;
            qwh[idx] = (f16)v;
        }
        if (idx < 128 * 128) pwh[idx] = (f16)pw[idx];
        if (idx < 384) qbs[idx] = qb[idx] * (idx < 128 ? QSC : 1.f);
        if (idx < 10240) rpbp[idx] = (idx < 4 * RPBSZ) ? rpb[idx] * LOG2E : 0.f;
    } else if (b < 216) {
        // b2s[i] = (qb[i] + qw[i,:]·pb) * sc_i ; 16 lanes per output, shuffle-reduce
        int t = (b - 192) * 256 + threadIdx.x;        // [0, 6144)
        int i = t >> 4, l = t & 15;
        if (i < 384) {
            float s = 0.f;
            #pragma unroll
            for (int j = l * 8; j < l * 8 + 8; j++) s += qw[i * 128 + j] * pb[j];
            s += __shfl_xor(s, 1); s += __shfl_xor(s, 2);
            s += __shfl_xor(s, 4); s += __shfl_xor(s, 8);
            if (l == 0) b2s[i] = (qb[i] + s) * (i < 128 ? QSC : 1.f);
        }
    } else {
        // w2h[i][k] = sc_i * sum_j qw[i][j] pw[j][k]
        const int bw = b - 216;                       // 0..11
        const int m0 = (bw & 1) * 64;                 // k-tile
        const int n0 = (bw >> 1) * 64;                // i-tile
        const int tid = threadIdx.x;
        const int w = tid >> 6, lane = tid & 63, quad = lane >> 4, nn = lane & 15;
        const int krow = m0 + w * 16 + nn;
        f16x8 af[4];
        #pragma unroll
        for (int ks = 0; ks < 4; ks++) {
            union { f16 e[8]; f16x8 v; } t;
            #pragma unroll
            for (int e = 0; e < 8; e++)
                t.e[e] = (f16)pw[(ks * 32 + quad * 8 + e) * 128 + krow];
            af[ks] = t.v;
        }
        f32x4 acc[4] = {};
        #pragma unroll
        for (int nt = 0; nt < 4; nt++) {
            int irow = n0 + nt * 16 + nn;
            #pragma unroll
            for (int ks = 0; ks < 4; ks++) {
                const float* qr = &qw[(size_t)irow * 128 + ks * 32 + quad * 8];
                float4 a = *(const float4*)qr, bq = *(const float4*)(qr + 4);
                PkU u0, u1, u2, u3;
                u0.h = __builtin_amdgcn_cvt_pkrtz(a.x, a.y);
                u1.h = __builtin_amdgcn_cvt_pkrtz(a.z, a.w);
                u2.h = __builtin_amdgcn_cvt_pkrtz(bq.x, bq.y);
                u3.h = __builtin_amdgcn_cvt_pkrtz(bq.z, bq.w);
                union { unsigned u[4]; f16x8 v; } bb;
                bb.u[0] = u0.u; bb.u[1] = u1.u; bb.u[2] = u2.u; bb.u[3] = u3.u;
                acc[nt] = __builtin_amdgcn_mfma_f32_16x16x32_f16(af[ks], bb.v, acc[nt], 0, 0, 0);
            }
        }
        #pragma unroll
        for (int nt = 0; nt < 4; nt++) {
            int i = n0 + nt * 16 + nn;
            float sc = (i < 128) ? QSC : 1.f;
            PkU p0, p1;
            p0.h = __builtin_amdgcn_cvt_pkrtz(acc[nt][0] * sc, acc[nt][1] * sc);
            p1.h = __builtin_amdgcn_cvt_pkrtz(acc[nt][2] * sc, acc[nt][3] * sc);
            *(uint2*)&w2h[(size_t)i * 128 + m0 + w * 16 + quad * 4] = make_uint2(p0.u, p1.u);
        }
    }
}

// ---------- fusion GEMM: yh = relu(cat @ lwh^T + lb); grid (352, 2) ----------
__global__ __launch_bounds__(256) void fusion_gemm(
    const float* __restrict__ x, const float* __restrict__ cond, const float* __restrict__ mask,
    const f16* __restrict__ lwh, const float* __restrict__ lb, f16* __restrict__ yh)
{
    __shared__ __align__(16) f16 Alds[64 * 168];
    const int m0 = blockIdx.x * 64, n0 = blockIdx.y * 64;
    const int tid = threadIdx.x;
    const int w = tid >> 6, lane = tid & 63, quad = lane >> 4, nn = lane & 15;

    {   // stage cat rows (f16)
        int r = tid >> 2, cpart = tid & 3;
        size_t pos = m0 + r;
        *(uint4*)&Alds[r * 168 + 128 + cpart * 8] = make_uint4(0, 0, 0, 0);
        const float* xr = x + pos * 128 + cpart * 32;
        #pragma unroll
        for (int t = 0; t < 4; t++) {
            float4 a = *(const float4*)(xr + t * 8);
            float4 b = *(const float4*)(xr + t * 8 + 4);
            PkU p0, p1, p2, p3;
            p0.h = __builtin_amdgcn_cvt_pkrtz(a.x, a.y);
            p1.h = __builtin_amdgcn_cvt_pkrtz(a.z, a.w);
            p2.h = __builtin_amdgcn_cvt_pkrtz(b.x, b.y);
            p3.h = __builtin_amdgcn_cvt_pkrtz(b.z, b.w);
            *(uint4*)&Alds[r * 168 + cpart * 32 + t * 8] = make_uint4(p0.u, p1.u, p2.u, p3.u);
        }
        if (cpart == 0) {
            Alds[r * 168 + 128] = (f16)cond[pos * 2];
            Alds[r * 168 + 129] = (f16)cond[pos * 2 + 1];
            Alds[r * 168 + 130] = (f16)mask[pos];
        }
    }
    __syncthreads();

    const int oc = n0 + w * 16 + nn;
    f16x8 af[5];
    #pragma unroll
    for (int ks = 0; ks < 5; ks++)
        af[ks] = *(const f16x8*)&lwh[(size_t)oc * 160 + ks * 32 + quad * 8];
    f32x4 acc[4] = {};
    #pragma unroll
    for (int ks = 0; ks < 5; ks++)
        #pragma unroll
        for (int nt = 0; nt < 4; nt++) {
            f16x8 bf = *(const f16x8*)&Alds[(nt * 16 + nn) * 168 + ks * 32 + quad * 8];
            acc[nt] = __builtin_amdgcn_mfma_f32_16x16x32_f16(af[ks], bf, acc[nt], 0, 0, 0);
        }
    float bv[4];
    #pragma unroll
    for (int r = 0; r < 4; r++) bv[r] = lb[n0 + w * 16 + quad * 4 + r];
    #pragma unroll
    for (int nt = 0; nt < 4; nt++) {
        int pos = m0 + nt * 16 + nn;
        PkU p0, p1;
        p0.h = __builtin_amdgcn_cvt_pkrtz(fmaxf(acc[nt][0] + bv[0], 0.f), fmaxf(acc[nt][1] + bv[1], 0.f));
        p1.h = __builtin_amdgcn_cvt_pkrtz(fmaxf(acc[nt][2] + bv[2], 0.f), fmaxf(acc[nt][3] + bv[3], 0.f));
        *(uint2*)&yh[(size_t)pos * 128 + n0 + w * 16 + quad * 4] = make_uint2(p0.u, p1.u);
    }
}

// ---------- qkv GEMM: grid (352, 6); Q|K rows stride 256, V transposed ----------
__global__ __launch_bounds__(256) void gemm_qkv(
    const f16* __restrict__ A, const f16* __restrict__ W, const float* __restrict__ bias,
    f16* __restrict__ qkh, f16* __restrict__ vt)
{
    __shared__ __align__(16) f16 Alds[64 * 136];
    const int m0 = blockIdx.x * 64, n0 = blockIdx.y * 64;
    const int tid = threadIdx.x;
    const int w = tid >> 6, lane = tid & 63, quad = lane >> 4, nn = lane & 15;

    for (int i = tid; i < 1024; i += 256) {
        int r = i >> 4, c = i & 15;
        *(uint4*)&Alds[r * 136 + c * 8] = *(const uint4*)&A[(size_t)(m0 + r) * 128 + c * 8];
    }
    __syncthreads();

    const int oc = n0 + w * 16 + nn;
    f16x8 af[4];
    #pragma unroll
    for (int ks = 0; ks < 4; ks++)
        af[ks] = *(const f16x8*)&W[(size_t)oc * 128 + ks * 32 + quad * 8];
    f32x4 acc[4] = {};
    #pragma unroll
    for (int ks = 0; ks < 4; ks++)
        #pragma unroll
        for (int nt = 0; nt < 4; nt++) {
            f16x8 bf = *(const f16x8*)&Alds[(nt * 16 + nn) * 136 + ks * 32 + quad * 8];
            acc[nt] = __builtin_amdgcn_mfma_f32_16x16x32_f16(af[ks], bf, acc[nt], 0, 0, 0);
        }
    float bv[4];
    #pragma unroll
    for (int r = 0; r < 4; r++) bv[r] = bias[n0 + w * 16 + quad * 4 + r];

    if (n0 < 256) {
        #pragma unroll
        for (int nt = 0; nt < 4; nt++) {
            int pos = m0 + nt * 16 + nn;
            PkU p0, p1;
            p0.h = __builtin_amdgcn_cvt_pkrtz(acc[nt][0] + bv[0], acc[nt][1] + bv[1]);
            p1.h = __builtin_amdgcn_cvt_pkrtz(acc[nt][2] + bv[2], acc[nt][3] + bv[3]);
            *(uint2*)&qkh[(size_t)pos * 256 + n0 + w * 16 + quad * 4] = make_uint2(p0.u, p1.u);
        }
    } else {
        #pragma unroll
        for (int nt = 0; nt < 4; nt++) {
            int pos = m0 + nt * 16 + nn;
            #pragma unroll
            for (int r = 0; r < 4; r++) {
                int chg = n0 - 256 + w * 16 + quad * 4 + r;
                vt[(size_t)chg * NPAD + pos] = (f16)(acc[nt][r] + bv[r]);
            }
        }
    }
}

// ---------- final projection: grid (352, 2), fp32 out ----------
__global__ __launch_bounds__(256) void gemm_out(
    const f16* __restrict__ A, const f16* __restrict__ W, const float* __restrict__ bias,
    float* __restrict__ outp)
{
    __shared__ __align__(16) f16 Alds[64 * 136];
    const int m0 = blockIdx.x * 64, n0 = blockIdx.y * 64;
    const int tid = threadIdx.x;
    const int w = tid >> 6, lane = tid & 63, quad = lane >> 4, nn = lane & 15;

    for (int i = tid; i < 1024; i += 256) {
        int r = i >> 4, c = i & 15;
        *(uint4*)&Alds[r * 136 + c * 8] = *(const uint4*)&A[(size_t)(m0 + r) * 128 + c * 8];
    }
    __syncthreads();

    const int oc = n0 + w * 16 + nn;
    f16x8 af[4];
    #pragma unroll
    for (int ks = 0; ks < 4; ks++)
        af[ks] = *(const f16x8*)&W[(size_t)oc * 128 + ks * 32 + quad * 8];
    f32x4 acc[4] = {};
    #pragma unroll
    for (int ks = 0; ks < 4; ks++)
        #pragma unroll
        for (int nt = 0; nt < 4; nt++) {
            f16x8 bf = *(const f16x8*)&Alds[(nt * 16 + nn) * 136 + ks * 32 + quad * 8];
            acc[nt] = __builtin_amdgcn_mfma_f32_16x16x32_f16(af[ks], bf, acc[nt], 0, 0, 0);
        }
    float bv[4];
    #pragma unroll
    for (int r = 0; r < 4; r++) bv[r] = bias[n0 + w * 16 + quad * 4 + r];
    #pragma unroll
    for (int nt = 0; nt < 4; nt++) {
        int pos = m0 + nt * 16 + nn;
        f32x4 vv;
        #pragma unroll
        for (int r = 0; r < 4; r++) vv[r] = acc[nt][r] + bv[r];
        *(f32x4*)&outp[(size_t)pos * 128 + n0 + w * 16 + quad * 4] = vv;
    }
}

// ---------- MFMA neighborhood attention: 4x8 query tile, 2 waves key-split, pipelined ----------
// R12 body with halved query tile: grid (64,11,4) = 2816 blocks (2x wave parallelism),
// 2 qsets (32 queries), 28-row key window, wave w covers rows [w*14, w*14+14).
// K/V loads amortized over 2 qsets. rpb+mask folded into S-MFMA accumulator (exp2
// domain); l via MFMA-with-ones. Merge stride 25 floats (odd*4B: conflict-free).
__global__ __launch_bounds__(128) void attn_mfma(
    const f16* __restrict__ qkh,   // [N][256] = Q|K, Q pre-scaled by QSC
    const f16* __restrict__ vt,    // [128][NPAD]
    const float* __restrict__ rpbp,
    f16* __restrict__ ao)          // [N][128]
{
    const int i0 = blockIdx.x * 4;
    const int j0 = blockIdx.y * 8;
    const int h  = blockIdx.z;
    const int tid = threadIdx.x;
    const int w = tid >> 6, lane = tid & 63;
    const int quad = lane >> 4, nn = lane & 15;

    const int ri0 = min(max(i0 - 12, 0), TT - 28);
    const int rj0 = min(max(j0 - 12, 0), PP - WIN) & ~1;

    __shared__ f16 Plds[2][16][40];
    __shared__ __align__(16) float Olds[64][25];   // stride 25 floats (odd*4B): conflict-free

    int qi_[2], si_[2], dbb_[2];
    unsigned cm_[2];
    f16x8 qf[2];
    #pragma unroll
    for (int qs = 0; qs < 2; qs++) {
        int ql = qs * 16 + nn;                     // 0..31
        int qi = i0 + (ql >> 3), qj = j0 + (ql & 7);
        int si = min(max(qi - 12, 0), TT - WIN);
        int sj = min(max(qj - 12, 0), PP - WIN);
        qi_[qs] = qi; si_[qs] = si;
        cm_[qs] = 0x1FFFFFFu << (sj - rj0);        // shift <= 7
        dbb_[qs] = rj0 - qj + 24;
        qf[qs] = *(const f16x8*)&qkh[(size_t)(qi * PP + qj) * 256 + h * HD + quad * 8];
    }
    const float* rp_h = rpbp + h * RPBSZ;
    const f16* vbase = vt + (size_t)(h * HD + nn) * NPAD;
    const f16x8 onesv = {(f16)1.f, (f16)1.f, (f16)1.f, (f16)1.f,
                         (f16)1.f, (f16)1.f, (f16)1.f, (f16)1.f};

    f32x4 O[2][2] = {};    // [qset][ch-half]; regs = queries, lane nn = channel
    f32x4 lacc[2] = {};    // regs = queries

    const int b0 = min(rj0 + nn, PP - 1);
    const int b1 = min(rj0 + 16 + nn, PP - 1);
    const size_t koff = 128 + h * HD + quad * 8;

    // prologue: load chunk w*14
    int aa = ri0 + w * 14;
    const f16* rowK = qkh + (size_t)aa * PP * 256 + koff;
    f16x8 kf0 = *(const f16x8*)(rowK + (size_t)b0 * 256);
    f16x8 kf1 = *(const f16x8*)(rowK + (size_t)b1 * 256);
    const f16* vrow = vbase + aa * PP + rj0 + quad * 8;
    f16x8 vf0 = *(const f16x8u*)vrow;
    f16x8 vf1 = *(const f16x8u*)(vrow + (size_t)16 * NPAD);

    for (int c = 0; c < 14; c++) {
        // prefetch chunk aa+1 (last-iteration overshoot: aa+1 <= 256, lands in vt scratch)
        const f16* rowKn = qkh + (size_t)(aa + 1) * PP * 256 + koff;
        f16x8 nkf0 = *(const f16x8*)(rowKn + (size_t)b0 * 256);
        f16x8 nkf1 = *(const f16x8*)(rowKn + (size_t)b1 * 256);
        const f16* vrown = vbase + (aa + 1) * PP + rj0 + quad * 8;
        f16x8 nvf0 = *(const f16x8u*)vrown;
        f16x8 nvf1 = *(const f16x8u*)(vrown + (size_t)16 * NPAD);

        #pragma unroll
        for (int qs = 0; qs < 2; qs++) {
            unsigned vm = ((unsigned)(aa - si_[qs]) <= 24u) ? cm_[qs] : 0u;
            const float* rp = rp_h + (aa - qi_[qs] + 24) * RPBW + dbb_[qs];
            f32x4 ra = *(const f32x4u*)(rp + quad * 4);
            f32x4 rb = *(const f32x4u*)(rp + 16 + quad * 4);
            f32x4 za, zb;
            #pragma unroll
            for (int r = 0; r < 4; r++) {
                int kl0 = quad * 4 + r;
                za[r] = ((vm >> kl0) & 1u) ? ra[r] : -1e30f;
                zb[r] = ((vm >> (kl0 + 16)) & 1u) ? rb[r] : -1e30f;
            }
            f32x4 s0 = __builtin_amdgcn_mfma_f32_16x16x32_f16(kf0, qf[qs], za, 0, 0, 0);
            f32x4 s1 = __builtin_amdgcn_mfma_f32_16x16x32_f16(kf1, qf[qs], zb, 0, 0, 0);

            float p[8];
            #pragma unroll
            for (int r = 0; r < 4; r++) {
                p[r]     = EXP2(s0[r]);
                p[r + 4] = EXP2(s1[r]);
            }
            PkU a, b, cc, d;
            a.h  = __builtin_amdgcn_cvt_pkrtz(p[0], p[1]);
            b.h  = __builtin_amdgcn_cvt_pkrtz(p[2], p[3]);
            cc.h = __builtin_amdgcn_cvt_pkrtz(p[4], p[5]);
            d.h  = __builtin_amdgcn_cvt_pkrtz(p[6], p[7]);
            *(uint2*)&Plds[w][nn][quad * 4]      = make_uint2(a.u, b.u);
            *(uint2*)&Plds[w][nn][16 + quad * 4] = make_uint2(cc.u, d.u);
            f16x8 pf = *(const f16x8*)&Plds[w][nn][quad * 8];

            O[qs][0] = __builtin_amdgcn_mfma_f32_16x16x32_f16(pf, vf0, O[qs][0], 0, 0, 0);
            O[qs][1] = __builtin_amdgcn_mfma_f32_16x16x32_f16(pf, vf1, O[qs][1], 0, 0, 0);
            lacc[qs] = __builtin_amdgcn_mfma_f32_16x16x32_f16(pf, onesv, lacc[qs], 0, 0, 0);
        }
        kf0 = nkf0; kf1 = nkf1; vf0 = nvf0; vf1 = nvf1;
        aa++;
    }

    // ---- merge: wave1 stores partials, wave0 adds and finishes ----
    if (w == 1) {
        float* ob = Olds[lane];
        #pragma unroll
        for (int qs = 0; qs < 2; qs++) {
            *(f32x4u*)&ob[qs * 12]     = O[qs][0];
            *(f32x4u*)&ob[qs * 12 + 4] = O[qs][1];
            *(f32x4u*)&ob[qs * 12 + 8] = lacc[qs];
        }
    }
    __syncthreads();
    if (w == 0) {
        const float* ob = Olds[lane];
        #pragma unroll
        for (int qs = 0; qs < 2; qs++) {
            O[qs][0] += *(const f32x4u*)&ob[qs * 12];
            O[qs][1] += *(const f32x4u*)&ob[qs * 12 + 4];
            lacc[qs] += *(const f32x4u*)&ob[qs * 12 + 8];
            #pragma unroll
            for (int r = 0; r < 4; r++) {
                float li = 1.f / lacc[qs][r];
                int ql = qs * 16 + quad * 4 + r;
                int qi = i0 + (ql >> 3), qj = j0 + (ql & 7);
                size_t base = (size_t)(qi * PP + qj) * CC + h * HD;
                ao[base + nn]      = (f16)(O[qs][0][r] * li);
                ao[base + 16 + nn] = (f16)(O[qs][1][r] * li);
            }
        }
    }
}

extern "C" void kernel_launch(void* const* d_in, const int* in_sizes, int n_in,
                              void* d_out, int out_size, void* d_ws, size_t ws_size,
                              hipStream_t stream) {
    (void)in_sizes; (void)n_in; (void)out_size; (void)ws_size;
    const float* x    = (const float*)d_in[0];
    const float* cond = (const float*)d_in[1];
    const float* mask = (const float*)d_in[2];
    const float* lw   = (const float*)d_in[3];
    const float* lb   = (const float*)d_in[4];
    const float* qw   = (const float*)d_in[5];
    const float* qb   = (const float*)d_in[6];
    const float* rpb  = (const float*)d_in[7];
    const float* pw   = (const float*)d_in[8];
    const float* pb   = (const float*)d_in[9];
    float* outp       = (float*)d_out;

    float* ws   = (float*)d_ws;
    float* qbs  = ws;                 // 384
    float* b2s  = qbs + 384;          // 384
    float* rpbp = b2s + 384;          // 10240 padded
    f16* lwh  = (f16*)(rpbp + 10240);             // 128*160
    f16* qwh  = lwh + 20480;                      // 384*128
    f16* pwh  = qwh + 49152;                      // 128*128
    f16* w2h  = pwh + 16384;                      // 384*128
    f16* yh   = w2h + 49152;                      // NN*128
    f16* qkh  = yh + (size_t)NN * 128;            // NN*256 (Q|K)
    f16* vt   = qkh + (size_t)NN * 256;           // 128*NPAD
    f16* ao   = vt + (size_t)128 * NPAD;          // NN*128  (prefetch overshoot lands in vt/ao)

    prep<<<228, 256, 0, stream>>>(lw, qw, pw, qb, pb, rpb, lwh, qwh, pwh, w2h, qbs, b2s, rpbp);
    fusion_gemm<<<dim3(352, 2), 256, 0, stream>>>(x, cond, mask, lwh, lb, yh);
    gemm_qkv<<<dim3(352, 6), 256, 0, stream>>>(yh, qwh, qbs, qkh, vt);
    attn_mfma<<<dim3(TT / 4, PP / 8, HEADS), 128, 0, stream>>>(qkh, vt, rpbp, ao);
    gemm_qkv<<<dim3(352, 6), 256, 0, stream>>>(ao, w2h, b2s, qkh, vt);   // fused proj+qkv
    attn_mfma<<<dim3(TT / 4, PP / 8, HEADS), 128, 0, stream>>>(qkh, vt, rpbp, ao);
    gemm_out<<<dim3(352, 2), 256, 0, stream>>>(ao, pwh, pb, outp);
}